// Round 8
// baseline (295.955 us; speedup 1.0000x reference)
//
#include <hip/hip_runtime.h>

#define B_ 8
#define T_ 32
#define N_ 500
#define DP 200
#define DC 128
#define H_ 4
#define U_ 64
#define NP 512           // padded N
#define COLS (T_ * U_)   // 2048

typedef __attribute__((ext_vector_type(8))) short bf16x8;
typedef __attribute__((ext_vector_type(4))) float f32x4;
typedef __attribute__((ext_vector_type(2))) float f32x2;

__device__ __forceinline__ ushort f2bf(float f) {
    unsigned u = __float_as_uint(f);
    unsigned r = (u + 0x7FFFu + ((u >> 16) & 1u)) >> 16;  // RTNE
    return (ushort)r;
}

// packed f32 add with uniform SGPR-pair src0 (guaranteed scalar operand)
__device__ __forceinline__ f32x2 pk_add_sv(unsigned long long sp, f32x2 dp) {
    f32x2 t;
    asm("v_pk_add_f32 %0, %1, %2" : "=v"(t) : "s"(sp), "v"(dp));
    return t;
}

#define MFMA __builtin_amdgcn_mfma_f32_16x16x32_bf16

// ---------------------------------------------------------------------------
// WT[h][u][d] = bf16(0.25 * Wmsg[h][d][u])  (0.25 = head mean, exact pow2)
__global__ void prep_wT(const float* __restrict__ Wmsg, ushort* __restrict__ WT) {
    int idx = blockIdx.x * 256 + threadIdx.x;
    int h = idx >> 13, u = (idx >> 7) & 63, d = idx & 127;
    WT[idx] = f2bf(0.25f * Wmsg[((size_t)h * DC + d) * U_ + u]);
}

// ---------------------------------------------------------------------------
// Projections for ALL heads, 4 node-rows per block. hsrc/hdst [B,H,N,U] fp32.
// dst waves also emit qv[b,h,n] = sum_u a[h,u]*hdst[b,h,n,u].
__global__ void __launch_bounds__(512) proj_all(
    const float* __restrict__ prev, const float* __restrict__ Wsrc,
    const float* __restrict__ Wdst, const float* __restrict__ a_all,
    float* __restrict__ hsrc, float* __restrict__ hdst,
    float* __restrict__ qv)
{
    __shared__ float rows[4 * DP];
    const int tid = threadIdx.x;
    const int bn0 = blockIdx.x * 4;
    for (int e = tid; e < 4 * DP; e += 512) rows[e] = prev[(size_t)bn0 * DP + e];
    __syncthreads();
    const int u = tid & 63;
    const int h = (tid >> 6) & 3;
    const int isdst = tid >> 8;
    const float* W = (isdst ? Wdst : Wsrc) + (size_t)h * DP * U_;
    float a0 = 0.f, a1 = 0.f, a2 = 0.f, a3 = 0.f;
#pragma unroll 4
    for (int d = 0; d < DP; ++d) {
        float w = W[d * U_ + u];
        a0 = fmaf(rows[d], w, a0);
        a1 = fmaf(rows[DP + d], w, a1);
        a2 = fmaf(rows[2 * DP + d], w, a2);
        a3 = fmaf(rows[3 * DP + d], w, a3);
    }
    float acc[4] = {a0, a1, a2, a3};
    float* o = isdst ? hdst : hsrc;
#pragma unroll
    for (int r = 0; r < 4; ++r) {
        int bn = bn0 + r, b = bn / N_, n = bn - b * N_;
        o[(((size_t)b * H_ + h) * N_ + n) * U_ + u] = acc[r];
    }
    if (isdst) {
        const int lane = tid & 63;
        const float av = a_all[(size_t)h * U_ + lane];
#pragma unroll
        for (int r = 0; r < 4; ++r) {
            float v = acc[r] * av;
            for (int off = 1; off < 64; off <<= 1) v += __shfl_xor(v, off);
            if (lane == 0) {
                int bn = bn0 + r, b = bn / N_, n = bn - b * N_;
                qv[((size_t)b * H_ + h) * NP + n] = v;
            }
        }
    }
}

// ---------------------------------------------------------------------------
// Scores + softmax. lrelu(x)=0.6x+0.4|x|; row-constant 0.6*P_i cancels ->
// score' = 0.6*Q_j + 0.4*sum_u a_u*|s_iu+d_ju|.
__global__ void __launch_bounds__(512) attn_softmax9(
    const float* __restrict__ hsrc, const float* __restrict__ hdst,
    const float* __restrict__ a_all, const float* __restrict__ qv,
    ushort* __restrict__ attnB)
{
    const int i0 = blockIdx.x * 8, b = blockIdx.y, h = blockIdx.z;
    const int tid = threadIdx.x;
    __shared__ float red[8 * 8];  // [wave][row]
    __shared__ float s_mx[8], s_rs[8];

    const float* ap = a_all + (size_t)h * U_;
    const float* hb = hsrc + (((size_t)b * H_ + h) * N_) * U_;
    const unsigned long long* sr8[8];
#pragma unroll
    for (int r = 0; r < 8; ++r)
        sr8[r] = (const unsigned long long*)
            (hb + (size_t)min(i0 + r, N_ - 1) * U_);   // uniform rows

    const int j = tid;
    const bool valid = j < N_;
    const float4* dp =
        (const float4*)&hdst[(((size_t)b * H_ + h) * N_ + (valid ? j : 0)) * U_];
    const float qj = qv[((size_t)b * H_ + h) * NP + j];   // garbage in pad: masked

    float av[8] = {0.f, 0.f, 0.f, 0.f, 0.f, 0.f, 0.f, 0.f};
#pragma unroll 1
    for (int kc = 0; kc < 8; ++kc) {         // SEQUENTIAL: 8 chunks of 8
        const int o = kc * 8;
        float4 A = dp[kc * 2 + 0];
        float4 Bv = dp[kc * 2 + 1];
        f32x2 dvp[4];
        dvp[0] = (f32x2){A.x, A.y};  dvp[1] = (f32x2){A.z, A.w};
        dvp[2] = (f32x2){Bv.x, Bv.y}; dvp[3] = (f32x2){Bv.z, Bv.w};
#pragma unroll
        for (int p = 0; p < 4; ++p) {
            const float a_lo = ap[o + p * 2];      // uniform -> SGPR
            const float a_hi = ap[o + p * 2 + 1];
#pragma unroll
            for (int r = 0; r < 8; ++r) {
                f32x2 t = pk_add_sv(sr8[r][kc * 4 + p], dvp[p]);
                av[r] = fmaf(fabsf(t.x), a_lo, av[r]);
                av[r] = fmaf(fabsf(t.y), a_hi, av[r]);
            }
        }
    }
    const float q6 = 0.6f * qj;
    float sc[8];
#pragma unroll
    for (int r = 0; r < 8; ++r)
        sc[r] = valid ? fmaf(0.4f, av[r], q6) : -1e30f;

    const int wave = tid >> 6, lane = tid & 63;
#pragma unroll
    for (int r = 0; r < 8; ++r) {
        float m = sc[r];
        for (int off = 1; off < 64; off <<= 1) m = fmaxf(m, __shfl_xor(m, off));
        if (lane == 0) red[wave * 8 + r] = m;
    }
    __syncthreads();
    if (tid < 8) {
        float mm = red[tid];
        for (int w = 1; w < 8; ++w) mm = fmaxf(mm, red[w * 8 + tid]);
        s_mx[tid] = mm;
    }
    __syncthreads();
    float e[8];
#pragma unroll
    for (int r = 0; r < 8; ++r) {
        e[r] = __expf(sc[r] - s_mx[r]);   // invalid j: exp(-1e30-mx) = 0
        float s = e[r];
        for (int off = 1; off < 64; off <<= 1) s += __shfl_xor(s, off);
        if (lane == 0) red[wave * 8 + r] = s;
    }
    __syncthreads();
    if (tid < 8) {
        float ss = 0.f;
        for (int w = 0; w < 8; ++w) ss += red[w * 8 + tid];
        s_rs[tid] = 1.0f / ss;
    }
    __syncthreads();
#pragma unroll
    for (int r = 0; r < 8; ++r)           // unconditional: pad j -> exact 0
        attnB[(((size_t)b * H_ + h) * NP + i0 + r) * NP + j] =
            f2bf(e[r] * s_rs[r]);
}

// ---------------------------------------------------------------------------
// R15 FUSED msg+gemm: msgT intermediate ELIMINATED (was 64MiB write + 268MB
// re-read, 4 msg_all variants all pinned at 58-64us). Block (t, n-half, b):
// per m-chunk stage curr->As once (reused over heads); per head form
// msg[128m x 64u] via MFMA into dbuf Ms[u][m] (16B-unit XOR swizzle:
// write 8B at unit^(u&7), read b128 at single unit^(u&7)); then out-GEMM
// A=Ms (u-rows, k=m), B=attn rows straight from L3-resident attnB.
// acc[u=64][n=32]/wave persists across all 16 (h,mc) segments (K=2048).
__global__ void __launch_bounds__(512) fused_mg(
    const float* __restrict__ curr, const ushort* __restrict__ WT,
    const ushort* __restrict__ attnB, float* __restrict__ out)
{
    __shared__ ushort As[128 * 136];     // curr chunk [m][d], pad+8
    __shared__ ushort Ms[2][64 * 128];   // msg [u][m 16B-unit swizzled], dbuf
    const int tid = threadIdx.x;
    const int t = blockIdx.x, nh = blockIdx.y, b = blockIdx.z;
    const int wave = tid >> 6, lane = tid & 63;
    const int r15 = lane & 15, quad = lane >> 4;
    const int wrow = (wave >> 1) * 32;   // msg-phase m-group
    const int wu = wave & 1;             // msg-phase u-half
    const int n0 = nh * 256 + wave * 32; // out-phase n-range base

    const float* cbase = curr + (size_t)(b * T_ + t) * N_ * DC;
    const ushort* abase = attnB + (((size_t)b * H_) * NP) * NP;

    f32x4 acc[4][2] = {};                // [u-tile][n-tile]

#pragma unroll 1
    for (int mc = 0; mc < 4; ++mc) {
        if (mc) __syncthreads();         // prior reads of As / Ms[p1] done
        // stage curr chunk [128 m][128 d] -> bf16 (0-fill pad m)
#pragma unroll
        for (int it = 0; it < 8; ++it) {
            int e = it * 2048 + tid * 4;
            int r = e >> 7, c = e & 127;
            int gm = mc * 128 + r;
            float4 v; v.x = v.y = v.z = v.w = 0.f;
            if (gm < N_) v = *(const float4*)&cbase[(size_t)gm * DC + c];
            ushort4 o;
            o.x = f2bf(v.x); o.y = f2bf(v.y); o.z = f2bf(v.z); o.w = f2bf(v.w);
            *(ushort4*)&As[r * 136 + c] = o;
        }
        __syncthreads();

#pragma unroll 1
        for (int h = 0; h < H_; ++h) {
            const int p = h & 1;
            // ---- msg phase: form msg[128m x 64u] for (h, mc)
            const ushort* wh = WT + (size_t)h * U_ * DC
                             + (size_t)(wu * 32 + r15) * DC + quad * 8;
            f32x4 mg[2][2] = {};
#pragma unroll
            for (int ks = 0; ks < 4; ++ks) {
                bf16x8 bg0 = *(const bf16x8*)&wh[ks * 32];
                bf16x8 bg1 = *(const bf16x8*)&wh[16 * DC + ks * 32];
                bf16x8 a0 = *(const bf16x8*)&As[(wrow + r15) * 136 + ks * 32 + quad * 8];
                bf16x8 a1 = *(const bf16x8*)&As[(wrow + 16 + r15) * 136 + ks * 32 + quad * 8];
                mg[0][0] = MFMA(a0, bg0, mg[0][0], 0, 0, 0);
                mg[0][1] = MFMA(a0, bg1, mg[0][1], 0, 0, 0);
                mg[1][0] = MFMA(a1, bg0, mg[1][0], 0, 0, 0);
                mg[1][1] = MFMA(a1, bg1, mg[1][1], 0, 0, 0);
            }
#pragma unroll
            for (int f = 0; f < 2; ++f)
#pragma unroll
                for (int g = 0; g < 2; ++g) {
                    const int u = wu * 32 + g * 16 + r15;
                    const int mp = wrow + f * 16 + quad * 4;  // 4 consecutive m
                    const int unit = (mp >> 3) ^ (u & 7);
                    ushort4 o;
                    o.x = f2bf(mg[f][g][0]); o.y = f2bf(mg[f][g][1]);
                    o.z = f2bf(mg[f][g][2]); o.w = f2bf(mg[f][g][3]);
                    *(ushort4*)&Ms[p][u * 128 + unit * 8 + (quad & 1) * 4] = o;
                }
            __syncthreads();             // Ms[p] ready; Ms[p^1] reads (h-1) done

            // ---- out phase: acc += msg(u,k=m) x attn(n,k=m)
            const ushort* ab = abase + (size_t)h * NP * NP + mc * 128;
#pragma unroll
            for (int ks = 0; ks < 4; ++ks) {
                bf16x8 bat[2];
#pragma unroll
                for (int g = 0; g < 2; ++g)
                    bat[g] = *(const bf16x8*)
                        &ab[(size_t)(n0 + g * 16 + r15) * NP + ks * 32 + quad * 8];
#pragma unroll
                for (int f = 0; f < 4; ++f) {
                    const int u = f * 16 + r15;
                    const int unit = (ks * 4 + quad) ^ (u & 7);
                    bf16x8 am = *(const bf16x8*)&Ms[p][u * 128 + unit * 8];
#pragma unroll
                    for (int g = 0; g < 2; ++g)
                        acc[f][g] = MFMA(am, bat[g], acc[f][g], 0, 0, 0);
                }
            }
            // next h writes Ms[p^1] (disjoint); h+2 re-writes Ms[p] only after
            // the intervening barrier -> safe with 1 barrier per head.
        }
    }

    // epilogue: D row = u (quad*4+reg), col = n (r15)
#pragma unroll
    for (int f = 0; f < 4; ++f)
#pragma unroll
        for (int g = 0; g < 2; ++g) {
            const int n = n0 + g * 16 + r15;
            if (n < N_) {
                float4 v;
                v.x = acc[f][g][0]; v.y = acc[f][g][1];
                v.z = acc[f][g][2]; v.w = acc[f][g][3];
                *(float4*)&out[(((size_t)b * T_ + t) * N_ + n) * U_
                               + f * 16 + quad * 4] = v;
            }
        }
}

// ---------------------------------------------------------------------------
// FALLBACK (small ws): per-head msg + gemm, same layouts.
__global__ void __launch_bounds__(256) msg_mfma(
    const float* __restrict__ curr, const ushort* __restrict__ WTh,
    ushort* __restrict__ msgT)
{
    __shared__ ushort As[128 * 136];
    __shared__ ushort Bs[64 * 136];
    const int tid = threadIdx.x;
    const int m0 = blockIdx.x * 128, t = blockIdx.y, b = blockIdx.z;

    const float* cbase = curr + (size_t)(b * T_ + t) * N_ * DC;
#pragma unroll
    for (int it = 0; it < 16; ++it) {
        int e = it * 1024 + tid * 4;
        int r = e >> 7, c = e & 127;
        int gm = m0 + r;
        float4 v; v.x = v.y = v.z = v.w = 0.f;
        if (gm < N_) v = *(const float4*)&cbase[(size_t)gm * DC + c];
        ushort4 o;
        o.x = f2bf(v.x); o.y = f2bf(v.y); o.z = f2bf(v.z); o.w = f2bf(v.w);
        *(ushort4*)&As[r * 136 + c] = o;
    }
#pragma unroll
    for (int it = 0; it < 4; ++it) {
        int e = it * 2048 + tid * 8;
        int u = e >> 7, d = e & 127;
        *(uint4*)&Bs[u * 136 + d] = *(const uint4*)&WTh[u * 128 + d];
    }
    __syncthreads();

    const int wave = tid >> 6, lane = tid & 63;
    const int r15 = lane & 15, quad = lane >> 4;
    const int wm = wave >> 1, wu = wave & 1;

    f32x4 acc[4][2] = {};
#pragma unroll
    for (int ks = 0; ks < 4; ++ks) {
        bf16x8 af[4], bg[2];
#pragma unroll
        for (int f = 0; f < 4; ++f)
            af[f] = *(const bf16x8*)&As[(wm * 64 + f * 16 + r15) * 136 + ks * 32 + quad * 8];
#pragma unroll
        for (int g = 0; g < 2; ++g)
            bg[g] = *(const bf16x8*)&Bs[(wu * 32 + g * 16 + r15) * 136 + ks * 32 + quad * 8];
#pragma unroll
        for (int f = 0; f < 4; ++f)
#pragma unroll
            for (int g = 0; g < 2; ++g)
                acc[f][g] = MFMA(af[f], bg[g], acc[f][g], 0, 0, 0);
    }
#pragma unroll
    for (int f = 0; f < 4; ++f)
#pragma unroll
        for (int g = 0; g < 2; ++g) {
            int m = m0 + wm * 64 + f * 16 + quad * 4;
            int u = wu * 32 + g * 16 + r15;
            int col = t * U_ + u;
            ushort4 o;
            o.x = f2bf(acc[f][g][0]); o.y = f2bf(acc[f][g][1]);
            o.z = f2bf(acc[f][g][2]); o.w = f2bf(acc[f][g][3]);
            *(ushort4*)&msgT[((size_t)b * COLS + col) * NP + m] = o;
        }
}

__global__ void __launch_bounds__(256) gemm_mfma(
    const ushort* __restrict__ msgT, const ushort* __restrict__ attnB,
    float* __restrict__ out, int h, int init)
{
    __shared__ ushort As[64 * 72];
    __shared__ ushort Bs[64 * 72];
    const int tid = threadIdx.x;
    const int ct = blockIdx.x, it = blockIdx.y, b = blockIdx.z;

    const ushort* Ab = msgT + ((size_t)b * COLS + ct * 64) * NP;
    const ushort* Bb = attnB + (((size_t)b * H_ + h) * NP + it * 64) * NP;

    const int wave = tid >> 6, lane = tid & 63;
    const int r15 = lane & 15, quad = lane >> 4;
    const int wm = wave >> 1, wn = wave & 1;
    const int srow = tid >> 3, scol = (tid & 7) * 8;

    f32x4 acc[2][2] = {};
    for (int kk = 0; kk < NP; kk += 64) {
#pragma unroll
        for (int it2 = 0; it2 < 2; ++it2) {
            int rr = it2 * 32 + srow;
            *(uint4*)&As[rr * 72 + scol] = *(const uint4*)&Ab[(size_t)rr * NP + kk + scol];
            *(uint4*)&Bs[rr * 72 + scol] = *(const uint4*)&Bb[(size_t)rr * NP + kk + scol];
        }
        __syncthreads();
#pragma unroll
        for (int ks = 0; ks < 2; ++ks) {
            bf16x8 af[2], bg[2];
#pragma unroll
            for (int f = 0; f < 2; ++f)
                af[f] = *(const bf16x8*)&As[(wm * 32 + f * 16 + r15) * 72 + ks * 32 + quad * 8];
#pragma unroll
            for (int g = 0; g < 2; ++g)
                bg[g] = *(const bf16x8*)&Bs[(wn * 32 + g * 16 + r15) * 72 + ks * 32 + quad * 8];
#pragma unroll
            for (int f = 0; f < 2; ++f)
#pragma unroll
                for (int g = 0; g < 2; ++g)
                    acc[f][g] = MFMA(af[f], bg[g], acc[f][g], 0, 0, 0);
        }
        __syncthreads();
    }

    const int t = ct;
#pragma unroll
    for (int f = 0; f < 2; ++f)
#pragma unroll
        for (int g = 0; g < 2; ++g) {
            int u = wm * 32 + f * 16 + quad * 4;
            int i = it * 64 + wn * 32 + g * 16 + r15;
            if (i < N_) {
                float* op = out + (((size_t)b * T_ + t) * N_ + i) * U_ + u;
                float4 v;
                v.x = acc[f][g][0]; v.y = acc[f][g][1];
                v.z = acc[f][g][2]; v.w = acc[f][g][3];
                if (!init) {
                    float4 old = *(const float4*)op;
                    v.x += old.x; v.y += old.y; v.z += old.z; v.w += old.w;
                }
                *(float4*)op = v;
            }
        }
}

// ---------------------------------------------------------------------------
extern "C" void kernel_launch(void* const* d_in, const int* in_sizes, int n_in,
                              void* d_out, int out_size, void* d_ws, size_t ws_size,
                              hipStream_t stream)
{
    const float* prev = (const float*)d_in[0];
    const float* curr = (const float*)d_in[1];
    const float* Wsrc = (const float*)d_in[2];
    const float* Wdst = (const float*)d_in[3];
    const float* avec = (const float*)d_in[4];
    const float* Wmsg = (const float*)d_in[5];
    float* out = (float*)d_out;

    const size_t attnB_b = (size_t)B_ * H_ * NP * NP * 2;   // 16.78 MB
    const size_t msgT1_b = (size_t)B_ * COLS * NP * 2;      // 16.78 MB (fallback)
    const size_t WT_b    = (size_t)H_ * U_ * DC * 2;
    const size_t hx_b    = (size_t)B_ * H_ * N_ * U_ * 4;   // 4.1 MB
    const size_t qv_b    = (size_t)B_ * H_ * NP * 4;        // 64 KB

    const bool fused = ws_size >= attnB_b + WT_b + 2 * hx_b + qv_b;
    const size_t msg_b = fused ? 0 : msgT1_b;

    ushort* attnB = (ushort*)d_ws;
    ushort* msgT  = (ushort*)((char*)d_ws + attnB_b);       // fallback only
    ushort* WT    = (ushort*)((char*)d_ws + attnB_b + msg_b);
    float*  hsrc  = (float*)((char*)WT + WT_b);
    float*  hdst  = (float*)((char*)hsrc + hx_b);
    float*  qv    = (float*)((char*)hdst + hx_b);

    prep_wT<<<128, 256, 0, stream>>>(Wmsg, WT);
    proj_all<<<1000, 512, 0, stream>>>(prev, Wsrc, Wdst, avec, hsrc, hdst, qv);
    attn_softmax9<<<dim3(64, B_, H_), 512, 0, stream>>>(hsrc, hdst, avec, qv, attnB);

    if (fused) {
        fused_mg<<<dim3(T_, 2, B_), 512, 0, stream>>>(curr, WT, attnB, out);
    } else {
        for (int h = 0; h < H_; ++h) {
            msg_mfma<<<dim3(4, T_, B_), 256, 0, stream>>>(
                curr, WT + (size_t)h * U_ * DC, msgT);
            gemm_mfma<<<dim3(32, 8, B_), 256, 0, stream>>>(
                msgT, attnB, out, h, h == 0 ? 1 : 0);
        }
    }
}

// Round 10
// 266.206 us; speedup vs baseline: 1.1118x; 1.1118x over previous
//
#include <hip/hip_runtime.h>

#define B_ 8
#define T_ 32
#define N_ 500
#define DP 200
#define DC 128
#define H_ 4
#define U_ 64
#define NP 512           // padded N
#define COLS (T_ * U_)   // 2048
#define K4 (H_ * NP)     // 2048 fused K

typedef __attribute__((ext_vector_type(8))) short bf16x8;
typedef __attribute__((ext_vector_type(4))) float f32x4;
typedef __attribute__((ext_vector_type(2))) float f32x2;

typedef const __attribute__((address_space(1))) void* gcptr_t;
typedef __attribute__((address_space(3))) void* lptr_t;

// async 16B/lane global->LDS; lds base must be wave-uniform (dest = base + lane*16)
__device__ __forceinline__ void async16(const void* g, void* lds) {
    __builtin_amdgcn_global_load_lds((gcptr_t)g, (lptr_t)lds, 16, 0, 0);
}

__device__ __forceinline__ ushort f2bf(float f) {
    unsigned u = __float_as_uint(f);
    unsigned r = (u + 0x7FFFu + ((u >> 16) & 1u)) >> 16;  // RTNE
    return (ushort)r;
}

// packed f32 add with uniform SGPR-pair src0 (guaranteed scalar operand)
__device__ __forceinline__ f32x2 pk_add_sv(unsigned long long sp, f32x2 dp) {
    f32x2 t;
    asm("v_pk_add_f32 %0, %1, %2" : "=v"(t) : "s"(sp), "v"(dp));
    return t;
}

#define MFMA __builtin_amdgcn_mfma_f32_16x16x32_bf16

// ---------------------------------------------------------------------------
// PROJ v2 (R16): 8 node-rows per block (W re-read traffic halved), prep_wT
// folded into blocks <128 (one launch removed). hsrc/hdst [B,H,N,U] fp32;
// qv[b,h,n] = sum_u a[h,u]*hdst[b,h,n,u] (wave butterfly).
__global__ void __launch_bounds__(512) proj_all2(
    const float* __restrict__ prev, const float* __restrict__ Wsrc,
    const float* __restrict__ Wdst, const float* __restrict__ a_all,
    const float* __restrict__ Wmsg, float* __restrict__ hsrc,
    float* __restrict__ hdst, float* __restrict__ qv, ushort* __restrict__ WT)
{
    __shared__ float rows[8 * DP];
    const int tid = threadIdx.x;
    const int bn0 = blockIdx.x * 8;

    // folded prep: WT[h][u][d] = bf16(0.25 * Wmsg[h][d][u])
    if (blockIdx.x < 128 && tid < 256) {
        int idx = blockIdx.x * 256 + tid;
        int h = idx >> 13, u = (idx >> 7) & 63, d = idx & 127;
        WT[idx] = f2bf(0.25f * Wmsg[((size_t)h * DC + d) * U_ + u]);
    }

    for (int e = tid; e < 8 * DP; e += 512) rows[e] = prev[(size_t)bn0 * DP + e];
    __syncthreads();
    const int u = tid & 63;
    const int h = (tid >> 6) & 3;
    const int isdst = tid >> 8;
    const float* W = (isdst ? Wdst : Wsrc) + (size_t)h * DP * U_;
    float acc[8] = {};
#pragma unroll 4
    for (int d = 0; d < DP; ++d) {
        float w = W[d * U_ + u];
#pragma unroll
        for (int r = 0; r < 8; ++r)
            acc[r] = fmaf(rows[r * DP + d], w, acc[r]);
    }
    float* o = isdst ? hdst : hsrc;
#pragma unroll
    for (int r = 0; r < 8; ++r) {
        int bn = bn0 + r, b = bn / N_, n = bn - b * N_;
        o[(((size_t)b * H_ + h) * N_ + n) * U_ + u] = acc[r];
    }
    if (isdst) {
        const int lane = tid & 63;
        const float av = a_all[(size_t)h * U_ + lane];
#pragma unroll
        for (int r = 0; r < 8; ++r) {
            float v = acc[r] * av;
            for (int off = 1; off < 64; off <<= 1) v += __shfl_xor(v, off);
            if (lane == 0) {
                int bn = bn0 + r, b = bn / N_, n = bn - b * N_;
                qv[((size_t)b * H_ + h) * NP + n] = v;
            }
        }
    }
}

// ---------------------------------------------------------------------------
// Scores + softmax. lrelu(x)=0.6x+0.4|x|; row-constant 0.6*P_i cancels ->
// score' = 0.6*Q_j + 0.4*sum_u a_u*|s_iu+d_ju|.  (verified R4-R7)
__global__ void __launch_bounds__(512) attn_softmax9(
    const float* __restrict__ hsrc, const float* __restrict__ hdst,
    const float* __restrict__ a_all, const float* __restrict__ qv,
    ushort* __restrict__ attnB)
{
    const int i0 = blockIdx.x * 8, b = blockIdx.y, h = blockIdx.z;
    const int tid = threadIdx.x;
    __shared__ float red[8 * 8];  // [wave][row]
    __shared__ float s_mx[8], s_rs[8];

    const float* ap = a_all + (size_t)h * U_;
    const float* hb = hsrc + (((size_t)b * H_ + h) * N_) * U_;
    const unsigned long long* sr8[8];
#pragma unroll
    for (int r = 0; r < 8; ++r)
        sr8[r] = (const unsigned long long*)
            (hb + (size_t)min(i0 + r, N_ - 1) * U_);   // uniform rows

    const int j = tid;
    const bool valid = j < N_;
    const float4* dp =
        (const float4*)&hdst[(((size_t)b * H_ + h) * N_ + (valid ? j : 0)) * U_];
    const float qj = qv[((size_t)b * H_ + h) * NP + j];   // garbage in pad: masked

    float av[8] = {0.f, 0.f, 0.f, 0.f, 0.f, 0.f, 0.f, 0.f};
#pragma unroll 1
    for (int kc = 0; kc < 8; ++kc) {         // SEQUENTIAL: 8 chunks of 8
        const int o = kc * 8;
        float4 A = dp[kc * 2 + 0];
        float4 Bv = dp[kc * 2 + 1];
        f32x2 dvp[4];
        dvp[0] = (f32x2){A.x, A.y};  dvp[1] = (f32x2){A.z, A.w};
        dvp[2] = (f32x2){Bv.x, Bv.y}; dvp[3] = (f32x2){Bv.z, Bv.w};
#pragma unroll
        for (int p = 0; p < 4; ++p) {
            const float a_lo = ap[o + p * 2];      // uniform -> SGPR
            const float a_hi = ap[o + p * 2 + 1];
#pragma unroll
            for (int r = 0; r < 8; ++r) {
                f32x2 t = pk_add_sv(sr8[r][kc * 4 + p], dvp[p]);
                av[r] = fmaf(fabsf(t.x), a_lo, av[r]);
                av[r] = fmaf(fabsf(t.y), a_hi, av[r]);
            }
        }
    }
    const float q6 = 0.6f * qj;
    float sc[8];
#pragma unroll
    for (int r = 0; r < 8; ++r)
        sc[r] = valid ? fmaf(0.4f, av[r], q6) : -1e30f;

    const int wave = tid >> 6, lane = tid & 63;
#pragma unroll
    for (int r = 0; r < 8; ++r) {
        float m = sc[r];
        for (int off = 1; off < 64; off <<= 1) m = fmaxf(m, __shfl_xor(m, off));
        if (lane == 0) red[wave * 8 + r] = m;
    }
    __syncthreads();
    if (tid < 8) {
        float mm = red[tid];
        for (int w = 1; w < 8; ++w) mm = fmaxf(mm, red[w * 8 + tid]);
        s_mx[tid] = mm;
    }
    __syncthreads();
    float e[8];
#pragma unroll
    for (int r = 0; r < 8; ++r) {
        e[r] = __expf(sc[r] - s_mx[r]);   // invalid j: exp(-1e30-mx) = 0
        float s = e[r];
        for (int off = 1; off < 64; off <<= 1) s += __shfl_xor(s, off);
        if (lane == 0) red[wave * 8 + r] = s;
    }
    __syncthreads();
    if (tid < 8) {
        float ss = 0.f;
        for (int w = 0; w < 8; ++w) ss += red[w * 8 + tid];
        s_rs[tid] = 1.0f / ss;
    }
    __syncthreads();
#pragma unroll
    for (int r = 0; r < 8; ++r)           // unconditional: pad j -> exact 0
        attnB[(((size_t)b * H_ + h) * NP + i0 + r) * NP + j] =
            f2bf(e[r] * s_rs[r]);
}

// ---------------------------------------------------------------------------
// msg v5 (R7-verified, 58us): reg-loaded A + coalesced stores via LDS
// transpose (16KB, XOR chunk swizzle).
__global__ void __launch_bounds__(512) msg_all(
    const float* __restrict__ curr, const ushort* __restrict__ WT,
    ushort* __restrict__ msgT)
{
    __shared__ ushort st[64 * 128];   // [u][m' chunk-swizzled]
    const int tid = threadIdx.x;
    const int m0 = blockIdx.x * 128, t = blockIdx.y, b = blockIdx.z;
    const int wave = tid >> 6, lane = tid & 63;
    const int r15 = lane & 15, quad = lane >> 4;
    const int wrow = (wave >> 1) * 32;   // 4 row-groups of 32 (m)
    const int wu = wave & 1;             // u-half

    const float* cbase = curr + (size_t)(b * T_ + t) * N_ * DC;

    // A fragments (head-independent): af[f][ks], 8 bf16 each
    bf16x8 af[2][4];
#pragma unroll
    for (int f = 0; f < 2; ++f) {
        const int gm = min(m0 + wrow + f * 16 + r15, N_ - 1);
        const float* rp = cbase + (size_t)gm * DC + quad * 8;
#pragma unroll
        for (int ks = 0; ks < 4; ++ks) {
            float4 lo = *(const float4*)&rp[ks * 32];
            float4 hi = *(const float4*)&rp[ks * 32 + 4];
            bf16x8 v;
            v[0] = (short)f2bf(lo.x); v[1] = (short)f2bf(lo.y);
            v[2] = (short)f2bf(lo.z); v[3] = (short)f2bf(lo.w);
            v[4] = (short)f2bf(hi.x); v[5] = (short)f2bf(hi.y);
            v[6] = (short)f2bf(hi.z); v[7] = (short)f2bf(hi.w);
            af[f][ks] = v;
        }
    }

    // per-lane WT base: u = wu*32 + g*16 + r15, d = ks*32 + quad*8
    const ushort* wbase = WT + (size_t)(wu * 32 + r15) * DC + quad * 8;

    // read-back indices: thread owns row (=u) tid>>3, m-segment (tid&7)*16
    const int rrow = tid >> 3, rseg = tid & 7;

#pragma unroll 1
    for (int h = 0; h < H_; ++h) {
        const ushort* wh = wbase + (size_t)h * U_ * DC;
        f32x4 acc[2][2] = {};
#pragma unroll
        for (int ks = 0; ks < 4; ++ks) {
            bf16x8 bg[2];
#pragma unroll
            for (int g = 0; g < 2; ++g)
                bg[g] = *(const bf16x8*)&wh[(size_t)(g * 16) * DC + ks * 32];
#pragma unroll
            for (int f = 0; f < 2; ++f)
#pragma unroll
                for (int g = 0; g < 2; ++g)
                    acc[f][g] = MFMA(af[f][ks], bg[g], acc[f][g], 0, 0, 0);
        }
        if (h) __syncthreads();   // prior head's read phase done
#pragma unroll
        for (int f = 0; f < 2; ++f)
#pragma unroll
            for (int g = 0; g < 2; ++g) {
                const int u = wu * 32 + g * 16 + r15;
                const int mp = wrow + f * 16 + quad * 4;    // chunk-aligned
                const int c = (mp >> 2) ^ (u & 7);          // swizzled chunk
                ushort4 o;
                o.x = f2bf(acc[f][g][0]); o.y = f2bf(acc[f][g][1]);
                o.z = f2bf(acc[f][g][2]); o.w = f2bf(acc[f][g][3]);
                *(ushort4*)&st[u * 128 + c * 4] = o;
            }
        __syncthreads();
        // read 16 m (4 swizzled chunks) for row rrow, store 2x16B contiguous
        unsigned long long ch[4];
#pragma unroll
        for (int k = 0; k < 4; ++k) {
            const int c = (rseg * 4 + k) ^ (rrow & 7);
            ch[k] = *(const unsigned long long*)&st[rrow * 128 + c * 4];
        }
        ushort* gp = &msgT[(((size_t)b * H_ + h) * COLS + t * U_ + rrow) * NP
                           + m0 + rseg * 16];
        ((unsigned long long*)gp)[0] = ch[0];
        ((unsigned long long*)gp)[1] = ch[1];
        ((unsigned long long*)gp)[2] = ch[2];
        ((unsigned long long*)gp)[3] = ch[3];
    }
}

// ---------------------------------------------------------------------------
// GEMM v3 (R16): 512 threads / 8 waves on the SAME verified 128x128 tile +
// async16 + XOR swizzle. Per-wave staging halves (2 loads each tile) and
// 2 blocks x 8 waves = 16 waves/CU (was 8) -> cross-block overlap hides the
// per-K-step barrier drain. Wave map: wm=wave>>2 (t-half), wn=wave&3
// (i-quarter, 32 rows); acc[4u][2i].
__global__ void __launch_bounds__(512) gemm_big3(
    const ushort* __restrict__ msgT, const ushort* __restrict__ attnB,
    float* __restrict__ out)
{
    __shared__ ushort As[128 * 64];   // [row][chunk-swizzled 64 cols]
    __shared__ ushort Bs[128 * 64];
    const int tid = threadIdx.x;
    const int mt = blockIdx.x, nt = blockIdx.y, b = blockIdx.z;

    const int wave = tid >> 6, lane = tid & 63;
    const int r15 = lane & 15, quad = lane >> 4;
    const int wm = wave >> 2, wn = wave & 3;
    const int lrow = lane >> 3, lch = lane & 7;

    f32x4 acc[4][2] = {};
    for (int kk = 0; kk < K4; kk += 64) {
        const int hh = kk >> 9, ko = kk & (NP - 1);
        const ushort* Ab = msgT + (((size_t)b * H_ + hh) * COLS + mt * 128) * NP + ko;
        const ushort* Bb = attnB + (((size_t)b * H_ + hh) * NP + nt * 128) * NP + ko;
        // wave w stages rows [w*16, w*16+16) of both tiles: 2 loads x 8 rows
#pragma unroll
        for (int l = 0; l < 2; ++l) {
            const int R0 = wave * 16 + l * 8;          // wave-uniform
            const int row = R0 + lrow;
            const int gch = lch ^ (row & 7);
            async16(Ab + (size_t)row * NP + gch * 8, &As[R0 * 64]);
            async16(Bb + (size_t)row * NP + gch * 8, &Bs[R0 * 64]);
        }
        __syncthreads();   // compiler drains vmcnt before s_barrier
#pragma unroll
        for (int ks = 0; ks < 2; ++ks) {
            bf16x8 af[4], bg[2];
#pragma unroll
            for (int f = 0; f < 4; ++f) {
                int row = wm * 64 + f * 16 + r15;
                int c = (ks * 4 + quad) ^ (row & 7);
                af[f] = *(const bf16x8*)&As[row * 64 + c * 8];
            }
#pragma unroll
            for (int g = 0; g < 2; ++g) {
                int row = wn * 32 + g * 16 + r15;
                int c = (ks * 4 + quad) ^ (row & 7);
                bg[g] = *(const bf16x8*)&Bs[row * 64 + c * 8];
            }
#pragma unroll
            for (int f = 0; f < 4; ++f)
#pragma unroll
                for (int g = 0; g < 2; ++g)
                    acc[f][g] = MFMA(af[f], bg[g], acc[f][g], 0, 0, 0);
        }
        __syncthreads();
    }

    const int t = mt * 2 + wm;
#pragma unroll
    for (int f = 0; f < 4; ++f)
#pragma unroll
        for (int g = 0; g < 2; ++g) {
            int u = f * 16 + quad * 4;
            int i = nt * 128 + wn * 32 + g * 16 + r15;
            if (i < N_) {
                float4 v;
                v.x = acc[f][g][0]; v.y = acc[f][g][1];
                v.z = acc[f][g][2]; v.w = acc[f][g][3];
                *(float4*)&out[(((size_t)b * T_ + t) * N_ + i) * U_ + u] = v;
            }
        }
}

// ---------------------------------------------------------------------------
// FALLBACK (small ws): per-head msg + gemm, same layouts.
__global__ void __launch_bounds__(256) msg_mfma(
    const float* __restrict__ curr, const ushort* __restrict__ WTh,
    ushort* __restrict__ msgT)
{
    __shared__ ushort As[128 * 136];
    __shared__ ushort Bs[64 * 136];
    const int tid = threadIdx.x;
    const int m0 = blockIdx.x * 128, t = blockIdx.y, b = blockIdx.z;

    const float* cbase = curr + (size_t)(b * T_ + t) * N_ * DC;
#pragma unroll
    for (int it = 0; it < 16; ++it) {
        int e = it * 1024 + tid * 4;
        int r = e >> 7, c = e & 127;
        int gm = m0 + r;
        float4 v; v.x = v.y = v.z = v.w = 0.f;
        if (gm < N_) v = *(const float4*)&cbase[(size_t)gm * DC + c];
        ushort4 o;
        o.x = f2bf(v.x); o.y = f2bf(v.y); o.z = f2bf(v.z); o.w = f2bf(v.w);
        *(ushort4*)&As[r * 136 + c] = o;
    }
#pragma unroll
    for (int it = 0; it < 4; ++it) {
        int e = it * 2048 + tid * 8;
        int u = e >> 7, d = e & 127;
        *(uint4*)&Bs[u * 136 + d] = *(const uint4*)&WTh[u * 128 + d];
    }
    __syncthreads();

    const int wave = tid >> 6, lane = tid & 63;
    const int r15 = lane & 15, quad = lane >> 4;
    const int wm = wave >> 1, wu = wave & 1;

    f32x4 acc[4][2] = {};
#pragma unroll
    for (int ks = 0; ks < 4; ++ks) {
        bf16x8 af[4], bg[2];
#pragma unroll
        for (int f = 0; f < 4; ++f)
            af[f] = *(const bf16x8*)&As[(wm * 64 + f * 16 + r15) * 136 + ks * 32 + quad * 8];
#pragma unroll
        for (int g = 0; g < 2; ++g)
            bg[g] = *(const bf16x8*)&Bs[(wu * 32 + g * 16 + r15) * 136 + ks * 32 + quad * 8];
#pragma unroll
        for (int f = 0; f < 4; ++f)
#pragma unroll
            for (int g = 0; g < 2; ++g)
                acc[f][g] = MFMA(af[f], bg[g], acc[f][g], 0, 0, 0);
    }
#pragma unroll
    for (int f = 0; f < 4; ++f)
#pragma unroll
        for (int g = 0; g < 2; ++g) {
            int m = m0 + wm * 64 + f * 16 + quad * 4;
            int u = wu * 32 + g * 16 + r15;
            int col = t * U_ + u;
            ushort4 o;
            o.x = f2bf(acc[f][g][0]); o.y = f2bf(acc[f][g][1]);
            o.z = f2bf(acc[f][g][2]); o.w = f2bf(acc[f][g][3]);
            *(ushort4*)&msgT[((size_t)b * COLS + col) * NP + m] = o;
        }
}

__global__ void __launch_bounds__(256) gemm_mfma(
    const ushort* __restrict__ msgT, const ushort* __restrict__ attnB,
    float* __restrict__ out, int h, int init)
{
    __shared__ ushort As[64 * 72];
    __shared__ ushort Bs[64 * 72];
    const int tid = threadIdx.x;
    const int ct = blockIdx.x, it = blockIdx.y, b = blockIdx.z;

    const ushort* Ab = msgT + ((size_t)b * COLS + ct * 64) * NP;
    const ushort* Bb = attnB + (((size_t)b * H_ + h) * NP + it * 64) * NP;

    const int wave = tid >> 6, lane = tid & 63;
    const int r15 = lane & 15, quad = lane >> 4;
    const int wm = wave >> 1, wn = wave & 1;
    const int srow = tid >> 3, scol = (tid & 7) * 8;

    f32x4 acc[2][2] = {};
    for (int kk = 0; kk < NP; kk += 64) {
#pragma unroll
        for (int it2 = 0; it2 < 2; ++it2) {
            int rr = it2 * 32 + srow;
            *(uint4*)&As[rr * 72 + scol] = *(const uint4*)&Ab[(size_t)rr * NP + kk + scol];
            *(uint4*)&Bs[rr * 72 + scol] = *(const uint4*)&Bb[(size_t)rr * NP + kk + scol];
        }
        __syncthreads();
#pragma unroll
        for (int ks = 0; ks < 2; ++ks) {
            bf16x8 af[2], bg[2];
#pragma unroll
            for (int f = 0; f < 2; ++f)
                af[f] = *(const bf16x8*)&As[(wm * 32 + f * 16 + r15) * 72 + ks * 32 + quad * 8];
#pragma unroll
            for (int g = 0; g < 2; ++g)
                bg[g] = *(const bf16x8*)&Bs[(wn * 32 + g * 16 + r15) * 72 + ks * 32 + quad * 8];
#pragma unroll
            for (int f = 0; f < 2; ++f)
#pragma unroll
                for (int g = 0; g < 2; ++g)
                    acc[f][g] = MFMA(af[f], bg[g], acc[f][g], 0, 0, 0);
        }
        __syncthreads();
    }

    const int t = ct;
#pragma unroll
    for (int f = 0; f < 2; ++f)
#pragma unroll
        for (int g = 0; g < 2; ++g) {
            int u = wm * 32 + f * 16 + quad * 4;
            int i = it * 64 + wn * 32 + g * 16 + r15;
            if (i < N_) {
                float* op = out + (((size_t)b * T_ + t) * N_ + i) * U_ + u;
                float4 v;
                v.x = acc[f][g][0]; v.y = acc[f][g][1];
                v.z = acc[f][g][2]; v.w = acc[f][g][3];
                if (!init) {
                    float4 old = *(const float4*)op;
                    v.x += old.x; v.y += old.y; v.z += old.z; v.w += old.w;
                }
                *(float4*)op = v;
            }
        }
}

// ---------------------------------------------------------------------------
extern "C" void kernel_launch(void* const* d_in, const int* in_sizes, int n_in,
                              void* d_out, int out_size, void* d_ws, size_t ws_size,
                              hipStream_t stream)
{
    const float* prev = (const float*)d_in[0];
    const float* curr = (const float*)d_in[1];
    const float* Wsrc = (const float*)d_in[2];
    const float* Wdst = (const float*)d_in[3];
    const float* avec = (const float*)d_in[4];
    const float* Wmsg = (const float*)d_in[5];
    float* out = (float*)d_out;

    const size_t attnB_b = (size_t)B_ * H_ * NP * NP * 2;   // 16.78 MB
    const size_t msgT4_b = (size_t)B_ * H_ * COLS * NP * 2; // 67.1 MB
    const size_t msgT1_b = (size_t)B_ * COLS * NP * 2;      // 16.78 MB
    const size_t WT_b    = (size_t)H_ * U_ * DC * 2;
    const size_t hx_b    = (size_t)B_ * H_ * N_ * U_ * 4;   // 4.1 MB
    const size_t qv_b    = (size_t)B_ * H_ * NP * 4;        // 64 KB

    const bool fused = ws_size >= attnB_b + msgT4_b + WT_b + 2 * hx_b + qv_b;
    const size_t msg_b = fused ? msgT4_b : msgT1_b;

    ushort* attnB = (ushort*)d_ws;
    ushort* msgT  = (ushort*)((char*)d_ws + attnB_b);
    ushort* WT    = (ushort*)((char*)d_ws + attnB_b + msg_b);
    float*  hsrc  = (float*)((char*)WT + WT_b);
    float*  hdst  = (float*)((char*)hsrc + hx_b);
    float*  qv    = (float*)((char*)hdst + hx_b);

    proj_all2<<<500, 512, 0, stream>>>(prev, Wsrc, Wdst, avec, Wmsg,
                                       hsrc, hdst, qv, WT);
    attn_softmax9<<<dim3(64, B_, H_), 512, 0, stream>>>(hsrc, hdst, avec, qv, attnB);

    if (fused) {
        msg_all<<<dim3(4, T_, B_), 512, 0, stream>>>(curr, WT, msgT);
        gemm_big3<<<dim3(16, 4, B_), 512, 0, stream>>>(msgT, attnB, out);
    } else {
        for (int h = 0; h < H_; ++h) {
            msg_mfma<<<dim3(4, T_, B_), 256, 0, stream>>>(
                curr, WT + (size_t)h * U_ * DC, msgT);
            gemm_mfma<<<dim3(32, 8, B_), 256, 0, stream>>>(
                msgT, attnB, out, h, h == 0 ? 1 : 0);
        }
    }
}

// Round 11
// 262.166 us; speedup vs baseline: 1.1289x; 1.0154x over previous
//
#include <hip/hip_runtime.h>

#define B_ 8
#define T_ 32
#define N_ 500
#define DP 200
#define DC 128
#define H_ 4
#define U_ 64
#define NP 512           // padded N
#define COLS (T_ * U_)   // 2048
#define K4 (H_ * NP)     // 2048 fused K

typedef __attribute__((ext_vector_type(8))) short bf16x8;
typedef __attribute__((ext_vector_type(4))) float f32x4;
typedef __attribute__((ext_vector_type(2))) float f32x2;

typedef const __attribute__((address_space(1))) void* gcptr_t;
typedef __attribute__((address_space(3))) void* lptr_t;

// async 16B/lane global->LDS; lds base must be wave-uniform (dest = base + lane*16)
__device__ __forceinline__ void async16(const void* g, void* lds) {
    __builtin_amdgcn_global_load_lds((gcptr_t)g, (lptr_t)lds, 16, 0, 0);
}

__device__ __forceinline__ ushort f2bf(float f) {
    unsigned u = __float_as_uint(f);
    unsigned r = (u + 0x7FFFu + ((u >> 16) & 1u)) >> 16;  // RTNE
    return (ushort)r;
}

// packed f32 add with uniform SGPR-pair src0 (guaranteed scalar operand)
__device__ __forceinline__ f32x2 pk_add_sv(unsigned long long sp, f32x2 dp) {
    f32x2 t;
    asm("v_pk_add_f32 %0, %1, %2" : "=v"(t) : "s"(sp), "v"(dp));
    return t;
}

#define MFMA __builtin_amdgcn_mfma_f32_16x16x32_bf16

// ---------------------------------------------------------------------------
// PROJ v2 (R16-verified): 8 node-rows per block, prep_wT folded in.
__global__ void __launch_bounds__(512) proj_all2(
    const float* __restrict__ prev, const float* __restrict__ Wsrc,
    const float* __restrict__ Wdst, const float* __restrict__ a_all,
    const float* __restrict__ Wmsg, float* __restrict__ hsrc,
    float* __restrict__ hdst, float* __restrict__ qv, ushort* __restrict__ WT)
{
    __shared__ float rows[8 * DP];
    const int tid = threadIdx.x;
    const int bn0 = blockIdx.x * 8;

    // folded prep: WT[h][u][d] = bf16(0.25 * Wmsg[h][d][u])
    if (blockIdx.x < 128 && tid < 256) {
        int idx = blockIdx.x * 256 + tid;
        int h = idx >> 13, u = (idx >> 7) & 63, d = idx & 127;
        WT[idx] = f2bf(0.25f * Wmsg[((size_t)h * DC + d) * U_ + u]);
    }

    for (int e = tid; e < 8 * DP; e += 512) rows[e] = prev[(size_t)bn0 * DP + e];
    __syncthreads();
    const int u = tid & 63;
    const int h = (tid >> 6) & 3;
    const int isdst = tid >> 8;
    const float* W = (isdst ? Wdst : Wsrc) + (size_t)h * DP * U_;
    float acc[8] = {};
#pragma unroll 4
    for (int d = 0; d < DP; ++d) {
        float w = W[d * U_ + u];
#pragma unroll
        for (int r = 0; r < 8; ++r)
            acc[r] = fmaf(rows[r * DP + d], w, acc[r]);
    }
    float* o = isdst ? hdst : hsrc;
#pragma unroll
    for (int r = 0; r < 8; ++r) {
        int bn = bn0 + r, b = bn / N_, n = bn - b * N_;
        o[(((size_t)b * H_ + h) * N_ + n) * U_ + u] = acc[r];
    }
    if (isdst) {
        const int lane = tid & 63;
        const float av = a_all[(size_t)h * U_ + lane];
#pragma unroll
        for (int r = 0; r < 8; ++r) {
            float v = acc[r] * av;
            for (int off = 1; off < 64; off <<= 1) v += __shfl_xor(v, off);
            if (lane == 0) {
                int bn = bn0 + r, b = bn / N_, n = bn - b * N_;
                qv[((size_t)b * H_ + h) * NP + n] = v;
            }
        }
    }
}

// ---------------------------------------------------------------------------
// PHASE2 (R17): attn_softmax9 + msg_all co-scheduled in ONE dispatch.
// They are data-independent (attn: hsrc/hdst/qv; msg: curr/WT) and have
// complementary profiles (attn 58% VALU / no MFMA; msg idle-everything).
// 2:1 interleave (bid%3==2 -> msg) puts both types on every CU.
// Both bodies byte-identical to the R10-verified standalone kernels.
__global__ void __launch_bounds__(512) phase2(
    const float* __restrict__ hsrc, const float* __restrict__ hdst,
    const float* __restrict__ a_all, const float* __restrict__ qv,
    ushort* __restrict__ attnB,
    const float* __restrict__ curr, const ushort* __restrict__ WT,
    ushort* __restrict__ msgT)
{
    __shared__ char sh[64 * 128 * 2];   // msg: st tile / attn: red+mx+rs
    const int bid = blockIdx.x;
    const int tid = threadIdx.x;
    const int sel = bid % 3;

    if (sel == 2) {
        // ==================== msg body (R7/R10-verified v5) ==============
        ushort* st = (ushort*)sh;       // [u][m' chunk-swizzled]
        const int midx = bid / 3;
        const int m0 = (midx & 3) * 128, t = (midx >> 2) & 31, b = midx >> 7;
        const int wave = tid >> 6, lane = tid & 63;
        const int r15 = lane & 15, quad = lane >> 4;
        const int wrow = (wave >> 1) * 32;
        const int wu = wave & 1;

        const float* cbase = curr + (size_t)(b * T_ + t) * N_ * DC;

        bf16x8 af[2][4];
#pragma unroll
        for (int f = 0; f < 2; ++f) {
            const int gm = min(m0 + wrow + f * 16 + r15, N_ - 1);
            const float* rp = cbase + (size_t)gm * DC + quad * 8;
#pragma unroll
            for (int ks = 0; ks < 4; ++ks) {
                float4 lo = *(const float4*)&rp[ks * 32];
                float4 hi = *(const float4*)&rp[ks * 32 + 4];
                bf16x8 v;
                v[0] = (short)f2bf(lo.x); v[1] = (short)f2bf(lo.y);
                v[2] = (short)f2bf(lo.z); v[3] = (short)f2bf(lo.w);
                v[4] = (short)f2bf(hi.x); v[5] = (short)f2bf(hi.y);
                v[6] = (short)f2bf(hi.z); v[7] = (short)f2bf(hi.w);
                af[f][ks] = v;
            }
        }

        const ushort* wbase = WT + (size_t)(wu * 32 + r15) * DC + quad * 8;
        const int rrow = tid >> 3, rseg = tid & 7;

#pragma unroll 1
        for (int h = 0; h < H_; ++h) {
            const ushort* wh = wbase + (size_t)h * U_ * DC;
            f32x4 acc[2][2] = {};
#pragma unroll
            for (int ks = 0; ks < 4; ++ks) {
                bf16x8 bg[2];
#pragma unroll
                for (int g = 0; g < 2; ++g)
                    bg[g] = *(const bf16x8*)&wh[(size_t)(g * 16) * DC + ks * 32];
#pragma unroll
                for (int f = 0; f < 2; ++f)
#pragma unroll
                    for (int g = 0; g < 2; ++g)
                        acc[f][g] = MFMA(af[f][ks], bg[g], acc[f][g], 0, 0, 0);
            }
            if (h) __syncthreads();
#pragma unroll
            for (int f = 0; f < 2; ++f)
#pragma unroll
                for (int g = 0; g < 2; ++g) {
                    const int u = wu * 32 + g * 16 + r15;
                    const int mp = wrow + f * 16 + quad * 4;
                    const int c = (mp >> 2) ^ (u & 7);
                    ushort4 o;
                    o.x = f2bf(acc[f][g][0]); o.y = f2bf(acc[f][g][1]);
                    o.z = f2bf(acc[f][g][2]); o.w = f2bf(acc[f][g][3]);
                    *(ushort4*)&st[u * 128 + c * 4] = o;
                }
            __syncthreads();
            unsigned long long ch[4];
#pragma unroll
            for (int k = 0; k < 4; ++k) {
                const int c = (rseg * 4 + k) ^ (rrow & 7);
                ch[k] = *(const unsigned long long*)&st[rrow * 128 + c * 4];
            }
            ushort* gp = &msgT[(((size_t)b * H_ + h) * COLS + t * U_ + rrow) * NP
                               + m0 + rseg * 16];
            ((unsigned long long*)gp)[0] = ch[0];
            ((unsigned long long*)gp)[1] = ch[1];
            ((unsigned long long*)gp)[2] = ch[2];
            ((unsigned long long*)gp)[3] = ch[3];
        }
    } else {
        // ==================== attn body (R10-verified softmax9) ==========
        float* red  = (float*)sh;        // [wave][row] 64
        float* s_mx = red + 64;
        float* s_rs = s_mx + 8;
        const int aidx = (bid / 3) * 2 + sel;
        const int i0 = (aidx & 63) * 8, b = (aidx >> 6) & 7, h = aidx >> 9;

        const float* ap = a_all + (size_t)h * U_;
        const float* hb = hsrc + (((size_t)b * H_ + h) * N_) * U_;
        const unsigned long long* sr8[8];
#pragma unroll
        for (int r = 0; r < 8; ++r)
            sr8[r] = (const unsigned long long*)
                (hb + (size_t)min(i0 + r, N_ - 1) * U_);

        const int j = tid;
        const bool valid = j < N_;
        const float4* dp =
            (const float4*)&hdst[(((size_t)b * H_ + h) * N_ + (valid ? j : 0)) * U_];
        const float qj = qv[((size_t)b * H_ + h) * NP + j];

        float av[8] = {0.f, 0.f, 0.f, 0.f, 0.f, 0.f, 0.f, 0.f};
#pragma unroll 1
        for (int kc = 0; kc < 8; ++kc) {
            float4 A = dp[kc * 2 + 0];
            float4 Bv = dp[kc * 2 + 1];
            f32x2 dvp[4];
            dvp[0] = (f32x2){A.x, A.y};  dvp[1] = (f32x2){A.z, A.w};
            dvp[2] = (f32x2){Bv.x, Bv.y}; dvp[3] = (f32x2){Bv.z, Bv.w};
            const int o = kc * 8;
#pragma unroll
            for (int p = 0; p < 4; ++p) {
                const float a_lo = ap[o + p * 2];
                const float a_hi = ap[o + p * 2 + 1];
#pragma unroll
                for (int r = 0; r < 8; ++r) {
                    f32x2 t2 = pk_add_sv(sr8[r][kc * 4 + p], dvp[p]);
                    av[r] = fmaf(fabsf(t2.x), a_lo, av[r]);
                    av[r] = fmaf(fabsf(t2.y), a_hi, av[r]);
                }
            }
        }
        const float q6 = 0.6f * qj;
        float sc[8];
#pragma unroll
        for (int r = 0; r < 8; ++r)
            sc[r] = valid ? fmaf(0.4f, av[r], q6) : -1e30f;

        const int wave = tid >> 6, lane = tid & 63;
#pragma unroll
        for (int r = 0; r < 8; ++r) {
            float m = sc[r];
            for (int off = 1; off < 64; off <<= 1) m = fmaxf(m, __shfl_xor(m, off));
            if (lane == 0) red[wave * 8 + r] = m;
        }
        __syncthreads();
        if (tid < 8) {
            float mm = red[tid];
            for (int w = 1; w < 8; ++w) mm = fmaxf(mm, red[w * 8 + tid]);
            s_mx[tid] = mm;
        }
        __syncthreads();
        float e[8];
#pragma unroll
        for (int r = 0; r < 8; ++r) {
            e[r] = __expf(sc[r] - s_mx[r]);
            float s = e[r];
            for (int off = 1; off < 64; off <<= 1) s += __shfl_xor(s, off);
            if (lane == 0) red[wave * 8 + r] = s;
        }
        __syncthreads();
        if (tid < 8) {
            float ss = 0.f;
            for (int w = 0; w < 8; ++w) ss += red[w * 8 + tid];
            s_rs[tid] = 1.0f / ss;
        }
        __syncthreads();
#pragma unroll
        for (int r = 0; r < 8; ++r)
            attnB[(((size_t)b * H_ + h) * NP + i0 + r) * NP + j] =
                f2bf(e[r] * s_rs[r]);
    }
}

// ---------------------------------------------------------------------------
// attn standalone (fallback path only; identical body)
__global__ void __launch_bounds__(512) attn_softmax9(
    const float* __restrict__ hsrc, const float* __restrict__ hdst,
    const float* __restrict__ a_all, const float* __restrict__ qv,
    ushort* __restrict__ attnB)
{
    const int i0 = blockIdx.x * 8, b = blockIdx.y, h = blockIdx.z;
    const int tid = threadIdx.x;
    __shared__ float red[8 * 8];
    __shared__ float s_mx[8], s_rs[8];

    const float* ap = a_all + (size_t)h * U_;
    const float* hb = hsrc + (((size_t)b * H_ + h) * N_) * U_;
    const unsigned long long* sr8[8];
#pragma unroll
    for (int r = 0; r < 8; ++r)
        sr8[r] = (const unsigned long long*)
            (hb + (size_t)min(i0 + r, N_ - 1) * U_);

    const int j = tid;
    const bool valid = j < N_;
    const float4* dp =
        (const float4*)&hdst[(((size_t)b * H_ + h) * N_ + (valid ? j : 0)) * U_];
    const float qj = qv[((size_t)b * H_ + h) * NP + j];

    float av[8] = {0.f, 0.f, 0.f, 0.f, 0.f, 0.f, 0.f, 0.f};
#pragma unroll 1
    for (int kc = 0; kc < 8; ++kc) {
        const int o = kc * 8;
        float4 A = dp[kc * 2 + 0];
        float4 Bv = dp[kc * 2 + 1];
        f32x2 dvp[4];
        dvp[0] = (f32x2){A.x, A.y};  dvp[1] = (f32x2){A.z, A.w};
        dvp[2] = (f32x2){Bv.x, Bv.y}; dvp[3] = (f32x2){Bv.z, Bv.w};
#pragma unroll
        for (int p = 0; p < 4; ++p) {
            const float a_lo = ap[o + p * 2];
            const float a_hi = ap[o + p * 2 + 1];
#pragma unroll
            for (int r = 0; r < 8; ++r) {
                f32x2 t = pk_add_sv(sr8[r][kc * 4 + p], dvp[p]);
                av[r] = fmaf(fabsf(t.x), a_lo, av[r]);
                av[r] = fmaf(fabsf(t.y), a_hi, av[r]);
            }
        }
    }
    const float q6 = 0.6f * qj;
    float sc[8];
#pragma unroll
    for (int r = 0; r < 8; ++r)
        sc[r] = valid ? fmaf(0.4f, av[r], q6) : -1e30f;

    const int wave = tid >> 6, lane = tid & 63;
#pragma unroll
    for (int r = 0; r < 8; ++r) {
        float m = sc[r];
        for (int off = 1; off < 64; off <<= 1) m = fmaxf(m, __shfl_xor(m, off));
        if (lane == 0) red[wave * 8 + r] = m;
    }
    __syncthreads();
    if (tid < 8) {
        float mm = red[tid];
        for (int w = 1; w < 8; ++w) mm = fmaxf(mm, red[w * 8 + tid]);
        s_mx[tid] = mm;
    }
    __syncthreads();
    float e[8];
#pragma unroll
    for (int r = 0; r < 8; ++r) {
        e[r] = __expf(sc[r] - s_mx[r]);
        float s = e[r];
        for (int off = 1; off < 64; off <<= 1) s += __shfl_xor(s, off);
        if (lane == 0) red[wave * 8 + r] = s;
    }
    __syncthreads();
    if (tid < 8) {
        float ss = 0.f;
        for (int w = 0; w < 8; ++w) ss += red[w * 8 + tid];
        s_rs[tid] = 1.0f / ss;
    }
    __syncthreads();
#pragma unroll
    for (int r = 0; r < 8; ++r)
        attnB[(((size_t)b * H_ + h) * NP + i0 + r) * NP + j] =
            f2bf(e[r] * s_rs[r]);
}

// ---------------------------------------------------------------------------
// GEMM v3 (R10-verified): 512 threads / 8 waves, 128x128 tile, async16+swz.
__global__ void __launch_bounds__(512) gemm_big3(
    const ushort* __restrict__ msgT, const ushort* __restrict__ attnB,
    float* __restrict__ out)
{
    __shared__ ushort As[128 * 64];
    __shared__ ushort Bs[128 * 64];
    const int tid = threadIdx.x;
    const int mt = blockIdx.x, nt = blockIdx.y, b = blockIdx.z;

    const int wave = tid >> 6, lane = tid & 63;
    const int r15 = lane & 15, quad = lane >> 4;
    const int wm = wave >> 2, wn = wave & 3;
    const int lrow = lane >> 3, lch = lane & 7;

    f32x4 acc[4][2] = {};
    for (int kk = 0; kk < K4; kk += 64) {
        const int hh = kk >> 9, ko = kk & (NP - 1);
        const ushort* Ab = msgT + (((size_t)b * H_ + hh) * COLS + mt * 128) * NP + ko;
        const ushort* Bb = attnB + (((size_t)b * H_ + hh) * NP + nt * 128) * NP + ko;
#pragma unroll
        for (int l = 0; l < 2; ++l) {
            const int R0 = wave * 16 + l * 8;
            const int row = R0 + lrow;
            const int gch = lch ^ (row & 7);
            async16(Ab + (size_t)row * NP + gch * 8, &As[R0 * 64]);
            async16(Bb + (size_t)row * NP + gch * 8, &Bs[R0 * 64]);
        }
        __syncthreads();
#pragma unroll
        for (int ks = 0; ks < 2; ++ks) {
            bf16x8 af[4], bg[2];
#pragma unroll
            for (int f = 0; f < 4; ++f) {
                int row = wm * 64 + f * 16 + r15;
                int c = (ks * 4 + quad) ^ (row & 7);
                af[f] = *(const bf16x8*)&As[row * 64 + c * 8];
            }
#pragma unroll
            for (int g = 0; g < 2; ++g) {
                int row = wn * 32 + g * 16 + r15;
                int c = (ks * 4 + quad) ^ (row & 7);
                bg[g] = *(const bf16x8*)&Bs[row * 64 + c * 8];
            }
#pragma unroll
            for (int f = 0; f < 4; ++f)
#pragma unroll
                for (int g = 0; g < 2; ++g)
                    acc[f][g] = MFMA(af[f], bg[g], acc[f][g], 0, 0, 0);
        }
        __syncthreads();
    }

    const int t = mt * 2 + wm;
#pragma unroll
    for (int f = 0; f < 4; ++f)
#pragma unroll
        for (int g = 0; g < 2; ++g) {
            int u = f * 16 + quad * 4;
            int i = nt * 128 + wn * 32 + g * 16 + r15;
            if (i < N_) {
                float4 v;
                v.x = acc[f][g][0]; v.y = acc[f][g][1];
                v.z = acc[f][g][2]; v.w = acc[f][g][3];
                *(float4*)&out[(((size_t)b * T_ + t) * N_ + i) * U_ + u] = v;
            }
        }
}

// ---------------------------------------------------------------------------
// FALLBACK (small ws): per-head msg + gemm, same layouts.
__global__ void __launch_bounds__(256) msg_mfma(
    const float* __restrict__ curr, const ushort* __restrict__ WTh,
    ushort* __restrict__ msgT)
{
    __shared__ ushort As[128 * 136];
    __shared__ ushort Bs[64 * 136];
    const int tid = threadIdx.x;
    const int m0 = blockIdx.x * 128, t = blockIdx.y, b = blockIdx.z;

    const float* cbase = curr + (size_t)(b * T_ + t) * N_ * DC;
#pragma unroll
    for (int it = 0; it < 16; ++it) {
        int e = it * 1024 + tid * 4;
        int r = e >> 7, c = e & 127;
        int gm = m0 + r;
        float4 v; v.x = v.y = v.z = v.w = 0.f;
        if (gm < N_) v = *(const float4*)&cbase[(size_t)gm * DC + c];
        ushort4 o;
        o.x = f2bf(v.x); o.y = f2bf(v.y); o.z = f2bf(v.z); o.w = f2bf(v.w);
        *(ushort4*)&As[r * 136 + c] = o;
    }
#pragma unroll
    for (int it = 0; it < 4; ++it) {
        int e = it * 2048 + tid * 8;
        int u = e >> 7, d = e & 127;
        *(uint4*)&Bs[u * 136 + d] = *(const uint4*)&WTh[u * 128 + d];
    }
    __syncthreads();

    const int wave = tid >> 6, lane = tid & 63;
    const int r15 = lane & 15, quad = lane >> 4;
    const int wm = wave >> 1, wu = wave & 1;

    f32x4 acc[4][2] = {};
#pragma unroll
    for (int ks = 0; ks < 4; ++ks) {
        bf16x8 af[4], bg[2];
#pragma unroll
        for (int f = 0; f < 4; ++f)
            af[f] = *(const bf16x8*)&As[(wm * 64 + f * 16 + r15) * 136 + ks * 32 + quad * 8];
#pragma unroll
        for (int g = 0; g < 2; ++g)
            bg[g] = *(const bf16x8*)&Bs[(wu * 32 + g * 16 + r15) * 136 + ks * 32 + quad * 8];
#pragma unroll
        for (int f = 0; f < 4; ++f)
#pragma unroll
            for (int g = 0; g < 2; ++g)
                acc[f][g] = MFMA(af[f], bg[g], acc[f][g], 0, 0, 0);
    }
#pragma unroll
    for (int f = 0; f < 4; ++f)
#pragma unroll
        for (int g = 0; g < 2; ++g) {
            int m = m0 + wm * 64 + f * 16 + quad * 4;
            int u = wu * 32 + g * 16 + r15;
            int col = t * U_ + u;
            ushort4 o;
            o.x = f2bf(acc[f][g][0]); o.y = f2bf(acc[f][g][1]);
            o.z = f2bf(acc[f][g][2]); o.w = f2bf(acc[f][g][3]);
            *(ushort4*)&msgT[((size_t)b * COLS + col) * NP + m] = o;
        }
}

__global__ void __launch_bounds__(256) gemm_mfma(
    const ushort* __restrict__ msgT, const ushort* __restrict__ attnB,
    float* __restrict__ out, int h, int init)
{
    __shared__ ushort As[64 * 72];
    __shared__ ushort Bs[64 * 72];
    const int tid = threadIdx.x;
    const int ct = blockIdx.x, it = blockIdx.y, b = blockIdx.z;

    const ushort* Ab = msgT + ((size_t)b * COLS + ct * 64) * NP;
    const ushort* Bb = attnB + (((size_t)b * H_ + h) * NP + it * 64) * NP;

    const int wave = tid >> 6, lane = tid & 63;
    const int r15 = lane & 15, quad = lane >> 4;
    const int wm = wave >> 1, wn = wave & 1;
    const int srow = tid >> 3, scol = (tid & 7) * 8;

    f32x4 acc[2][2] = {};
    for (int kk = 0; kk < NP; kk += 64) {
#pragma unroll
        for (int it2 = 0; it2 < 2; ++it2) {
            int rr = it2 * 32 + srow;
            *(uint4*)&As[rr * 72 + scol] = *(const uint4*)&Ab[(size_t)rr * NP + kk + scol];
            *(uint4*)&Bs[rr * 72 + scol] = *(const uint4*)&Bb[(size_t)rr * NP + kk + scol];
        }
        __syncthreads();
#pragma unroll
        for (int ks = 0; ks < 2; ++ks) {
            bf16x8 af[2], bg[2];
#pragma unroll
            for (int f = 0; f < 2; ++f)
                af[f] = *(const bf16x8*)&As[(wm * 32 + f * 16 + r15) * 72 + ks * 32 + quad * 8];
#pragma unroll
            for (int g = 0; g < 2; ++g)
                bg[g] = *(const bf16x8*)&Bs[(wn * 32 + g * 16 + r15) * 72 + ks * 32 + quad * 8];
#pragma unroll
            for (int f = 0; f < 2; ++f)
#pragma unroll
                for (int g = 0; g < 2; ++g)
                    acc[f][g] = MFMA(af[f], bg[g], acc[f][g], 0, 0, 0);
        }
        __syncthreads();
    }

    const int t = ct;
#pragma unroll
    for (int f = 0; f < 2; ++f)
#pragma unroll
        for (int g = 0; g < 2; ++g) {
            int u = wm * 32 + f * 16 + quad * 4;
            int i = it * 64 + wn * 32 + g * 16 + r15;
            if (i < N_) {
                float* op = out + (((size_t)b * T_ + t) * N_ + i) * U_ + u;
                float4 v;
                v.x = acc[f][g][0]; v.y = acc[f][g][1];
                v.z = acc[f][g][2]; v.w = acc[f][g][3];
                if (!init) {
                    float4 old = *(const float4*)op;
                    v.x += old.x; v.y += old.y; v.z += old.z; v.w += old.w;
                }
                *(float4*)op = v;
            }
        }
}

// ---------------------------------------------------------------------------
extern "C" void kernel_launch(void* const* d_in, const int* in_sizes, int n_in,
                              void* d_out, int out_size, void* d_ws, size_t ws_size,
                              hipStream_t stream)
{
    const float* prev = (const float*)d_in[0];
    const float* curr = (const float*)d_in[1];
    const float* Wsrc = (const float*)d_in[2];
    const float* Wdst = (const float*)d_in[3];
    const float* avec = (const float*)d_in[4];
    const float* Wmsg = (const float*)d_in[5];
    float* out = (float*)d_out;

    const size_t attnB_b = (size_t)B_ * H_ * NP * NP * 2;   // 16.78 MB
    const size_t msgT4_b = (size_t)B_ * H_ * COLS * NP * 2; // 67.1 MB
    const size_t msgT1_b = (size_t)B_ * COLS * NP * 2;      // 16.78 MB
    const size_t WT_b    = (size_t)H_ * U_ * DC * 2;
    const size_t hx_b    = (size_t)B_ * H_ * N_ * U_ * 4;   // 4.1 MB
    const size_t qv_b    = (size_t)B_ * H_ * NP * 4;        // 64 KB

    const bool fused = ws_size >= attnB_b + msgT4_b + WT_b + 2 * hx_b + qv_b;
    const size_t msg_b = fused ? msgT4_b : msgT1_b;

    ushort* attnB = (ushort*)d_ws;
    ushort* msgT  = (ushort*)((char*)d_ws + attnB_b);
    ushort* WT    = (ushort*)((char*)d_ws + attnB_b + msg_b);
    float*  hsrc  = (float*)((char*)WT + WT_b);
    float*  hdst  = (float*)((char*)hsrc + hx_b);
    float*  qv    = (float*)((char*)hdst + hx_b);

    proj_all2<<<500, 512, 0, stream>>>(prev, Wsrc, Wdst, avec, Wmsg,
                                       hsrc, hdst, qv, WT);

    if (fused) {
        // attn (2048 blocks) + msg (1024 blocks) co-scheduled 2:1
        phase2<<<3072, 512, 0, stream>>>(hsrc, hdst, avec, qv, attnB,
                                         curr, WT, msgT);
        gemm_big3<<<dim3(16, 4, B_), 512, 0, stream>>>(msgT, attnB, out);
    } else {
        attn_softmax9<<<dim3(64, B_, H_), 512, 0, stream>>>(hsrc, hdst, avec, qv, attnB);
        for (int h = 0; h < H_; ++h) {
            msg_mfma<<<dim3(4, T_, B_), 256, 0, stream>>>(
                curr, WT + (size_t)h * U_ * DC, msgT);
            gemm_mfma<<<dim3(32, 8, B_), 256, 0, stream>>>(
                msgT, attnB, out, h, h == 0 ? 1 : 0);
        }
    }
}

// Round 12
// 256.616 us; speedup vs baseline: 1.1533x; 1.0216x over previous
//
#include <hip/hip_runtime.h>

#define B_ 8
#define T_ 32
#define N_ 500
#define DP 200
#define DC 128
#define H_ 4
#define U_ 64
#define NP 512           // padded N
#define COLS (T_ * U_)   // 2048
#define K4 (H_ * NP)     // 2048 fused K

typedef __attribute__((ext_vector_type(8))) short bf16x8;
typedef __attribute__((ext_vector_type(4))) float f32x4;
typedef __attribute__((ext_vector_type(2))) float f32x2;

typedef const __attribute__((address_space(1))) void* gcptr_t;
typedef __attribute__((address_space(3))) void* lptr_t;

// async 16B/lane global->LDS; lds base must be wave-uniform (dest = base + lane*16)
__device__ __forceinline__ void async16(const void* g, void* lds) {
    __builtin_amdgcn_global_load_lds((gcptr_t)g, (lptr_t)lds, 16, 0, 0);
}

__device__ __forceinline__ ushort f2bf(float f) {
    unsigned u = __float_as_uint(f);
    unsigned r = (u + 0x7FFFu + ((u >> 16) & 1u)) >> 16;  // RTNE
    return (ushort)r;
}

// packed f32 add with uniform SGPR-pair src0 (guaranteed scalar operand)
__device__ __forceinline__ f32x2 pk_add_sv(unsigned long long sp, f32x2 dp) {
    f32x2 t;
    asm("v_pk_add_f32 %0, %1, %2" : "=v"(t) : "s"(sp), "v"(dp));
    return t;
}

#define MFMA __builtin_amdgcn_mfma_f32_16x16x32_bf16

// ---------------------------------------------------------------------------
// PROJ v3 (R18): MFMA-ized. proj is a [4000x200]x[200x512] GEMM that ran on
// scalar fp32 VALU at ~65us with 75% stall. Split-bf16 (x=hi+lo, 3-term
// Ah*Bh+Ah*Bl+Al*Bh, rel err ~2e-5 << existing 4e-3 attnB quantization).
// 250 blocks x 16 rows; wave = 16 rows x 64 cols (head h=wave&3,
// src/dst=wave>>2). A from prev (2 float4/lane, hi/lo in-register);
// B from raw W (8 strided fp32 loads/frag, L2-hot 410KB; no prep kernel).
// K=200 -> 7 steps of 32, tail quad-masked. qv by dst waves via shfl.
// Fragment convention identical to session-verified msg_mfma.
__global__ void __launch_bounds__(512) proj_mfma(
    const float* __restrict__ prev, const float* __restrict__ Wsrc,
    const float* __restrict__ Wdst, const float* __restrict__ a_all,
    const float* __restrict__ Wmsg, float* __restrict__ hsrc,
    float* __restrict__ hdst, float* __restrict__ qv, ushort* __restrict__ WT)
{
    const int tid = threadIdx.x;
    // folded WT prep: WT[h][u][d] = bf16(0.25 * Wmsg[h][d][u])
    if (blockIdx.x < 128 && tid < 256) {
        int idx = blockIdx.x * 256 + tid;
        int h = idx >> 13, u = (idx >> 7) & 63, d = idx & 127;
        WT[idx] = f2bf(0.25f * Wmsg[((size_t)h * DC + d) * U_ + u]);
    }

    const int bn0 = blockIdx.x * 16;
    const int wave = tid >> 6, lane = tid & 63;
    const int r15 = lane & 15, quad = lane >> 4;
    const int h = wave & 3, isdst = wave >> 2;
    const float* W = (isdst ? Wdst : Wsrc) + (size_t)h * DP * U_;
    const float* ap = prev + (size_t)(bn0 + r15) * DP;   // A row (row = r15)

    f32x4 acc[4] = {};   // [g]: col u = g*16+r15, rows n = quad*4+reg

#pragma unroll 1
    for (int ks = 0; ks < 7; ++ks) {
        const int d0 = ks * 32 + quad * 8;
        bf16x8 ah = {}, al = {};
        if (d0 < DP) {                       // d0 mult of 8; 192+8=200 fits
            float av8[8];
            *(float4*)&av8[0] = *(const float4*)&ap[d0];
            *(float4*)&av8[4] = *(const float4*)&ap[d0 + 4];
#pragma unroll
            for (int e = 0; e < 8; ++e) {
                ushort hi = f2bf(av8[e]);
                float hf = __uint_as_float((unsigned)hi << 16);
                ah[e] = (short)hi;
                al[e] = (short)f2bf(av8[e] - hf);
            }
        }
#pragma unroll
        for (int g = 0; g < 4; ++g) {
            const int u = g * 16 + r15;
            bf16x8 bh = {}, bl = {};
            if (d0 < DP) {
#pragma unroll
                for (int e = 0; e < 8; ++e) {
                    float w = W[(size_t)(d0 + e) * U_ + u];
                    ushort hi = f2bf(w);
                    float hf = __uint_as_float((unsigned)hi << 16);
                    bh[e] = (short)hi;
                    bl[e] = (short)f2bf(w - hf);
                }
            }
            acc[g] = MFMA(ah, bh, acc[g], 0, 0, 0);
            acc[g] = MFMA(ah, bl, acc[g], 0, 0, 0);
            acc[g] = MFMA(al, bh, acc[g], 0, 0, 0);
        }
    }

    // store h[b,h,n,u]; D layout: row n = quad*4 + reg j, col u = g*16 + r15
    float* o = isdst ? hdst : hsrc;
#pragma unroll
    for (int j = 0; j < 4; ++j) {
        const int bn = bn0 + quad * 4 + j;
        const int b = bn / N_, n = bn - b * N_;
#pragma unroll
        for (int g = 0; g < 4; ++g)
            o[(((size_t)b * H_ + h) * N_ + n) * U_ + g * 16 + r15] = acc[g][j];
    }
    if (isdst) {   // qv[b,h,n] = sum_u a[h,u]*hdst[b,h,n,u]
#pragma unroll
        for (int j = 0; j < 4; ++j) {
            float s = 0.f;
#pragma unroll
            for (int g = 0; g < 4; ++g)
                s += acc[g][j] * a_all[(size_t)h * U_ + g * 16 + r15];
            s += __shfl_xor(s, 1); s += __shfl_xor(s, 2);
            s += __shfl_xor(s, 4); s += __shfl_xor(s, 8);
            if (r15 == 0) {
                const int bn = bn0 + quad * 4 + j;
                const int b = bn / N_, n = bn - b * N_;
                qv[((size_t)b * H_ + h) * NP + n] = s;
            }
        }
    }
}

// ---------------------------------------------------------------------------
// PHASE2 (R11-verified, 113us): attn_softmax9 + msg_all co-scheduled 2:1.
__global__ void __launch_bounds__(512) phase2(
    const float* __restrict__ hsrc, const float* __restrict__ hdst,
    const float* __restrict__ a_all, const float* __restrict__ qv,
    ushort* __restrict__ attnB,
    const float* __restrict__ curr, const ushort* __restrict__ WT,
    ushort* __restrict__ msgT)
{
    __shared__ char sh[64 * 128 * 2];   // msg: st tile / attn: red+mx+rs
    const int bid = blockIdx.x;
    const int tid = threadIdx.x;
    const int sel = bid % 3;

    if (sel == 2) {
        // ==================== msg body (R7/R10-verified v5) ==============
        ushort* st = (ushort*)sh;       // [u][m' chunk-swizzled]
        const int midx = bid / 3;
        const int m0 = (midx & 3) * 128, t = (midx >> 2) & 31, b = midx >> 7;
        const int wave = tid >> 6, lane = tid & 63;
        const int r15 = lane & 15, quad = lane >> 4;
        const int wrow = (wave >> 1) * 32;
        const int wu = wave & 1;

        const float* cbase = curr + (size_t)(b * T_ + t) * N_ * DC;

        bf16x8 af[2][4];
#pragma unroll
        for (int f = 0; f < 2; ++f) {
            const int gm = min(m0 + wrow + f * 16 + r15, N_ - 1);
            const float* rp = cbase + (size_t)gm * DC + quad * 8;
#pragma unroll
            for (int ks = 0; ks < 4; ++ks) {
                float4 lo = *(const float4*)&rp[ks * 32];
                float4 hi = *(const float4*)&rp[ks * 32 + 4];
                bf16x8 v;
                v[0] = (short)f2bf(lo.x); v[1] = (short)f2bf(lo.y);
                v[2] = (short)f2bf(lo.z); v[3] = (short)f2bf(lo.w);
                v[4] = (short)f2bf(hi.x); v[5] = (short)f2bf(hi.y);
                v[6] = (short)f2bf(hi.z); v[7] = (short)f2bf(hi.w);
                af[f][ks] = v;
            }
        }

        const ushort* wbase = WT + (size_t)(wu * 32 + r15) * DC + quad * 8;
        const int rrow = tid >> 3, rseg = tid & 7;

#pragma unroll 1
        for (int h = 0; h < H_; ++h) {
            const ushort* wh = wbase + (size_t)h * U_ * DC;
            f32x4 acc[2][2] = {};
#pragma unroll
            for (int ks = 0; ks < 4; ++ks) {
                bf16x8 bg[2];
#pragma unroll
                for (int g = 0; g < 2; ++g)
                    bg[g] = *(const bf16x8*)&wh[(size_t)(g * 16) * DC + ks * 32];
#pragma unroll
                for (int f = 0; f < 2; ++f)
#pragma unroll
                    for (int g = 0; g < 2; ++g)
                        acc[f][g] = MFMA(af[f][ks], bg[g], acc[f][g], 0, 0, 0);
            }
            if (h) __syncthreads();
#pragma unroll
            for (int f = 0; f < 2; ++f)
#pragma unroll
                for (int g = 0; g < 2; ++g) {
                    const int u = wu * 32 + g * 16 + r15;
                    const int mp = wrow + f * 16 + quad * 4;
                    const int c = (mp >> 2) ^ (u & 7);
                    ushort4 o;
                    o.x = f2bf(acc[f][g][0]); o.y = f2bf(acc[f][g][1]);
                    o.z = f2bf(acc[f][g][2]); o.w = f2bf(acc[f][g][3]);
                    *(ushort4*)&st[u * 128 + c * 4] = o;
                }
            __syncthreads();
            unsigned long long ch[4];
#pragma unroll
            for (int k = 0; k < 4; ++k) {
                const int c = (rseg * 4 + k) ^ (rrow & 7);
                ch[k] = *(const unsigned long long*)&st[rrow * 128 + c * 4];
            }
            ushort* gp = &msgT[(((size_t)b * H_ + h) * COLS + t * U_ + rrow) * NP
                               + m0 + rseg * 16];
            ((unsigned long long*)gp)[0] = ch[0];
            ((unsigned long long*)gp)[1] = ch[1];
            ((unsigned long long*)gp)[2] = ch[2];
            ((unsigned long long*)gp)[3] = ch[3];
        }
    } else {
        // ==================== attn body (R10-verified softmax9) ==========
        float* red  = (float*)sh;        // [wave][row] 64
        float* s_mx = red + 64;
        float* s_rs = s_mx + 8;
        const int aidx = (bid / 3) * 2 + sel;
        const int i0 = (aidx & 63) * 8, b = (aidx >> 6) & 7, h = aidx >> 9;

        const float* ap = a_all + (size_t)h * U_;
        const float* hb = hsrc + (((size_t)b * H_ + h) * N_) * U_;
        const unsigned long long* sr8[8];
#pragma unroll
        for (int r = 0; r < 8; ++r)
            sr8[r] = (const unsigned long long*)
                (hb + (size_t)min(i0 + r, N_ - 1) * U_);

        const int j = tid;
        const bool valid = j < N_;
        const float4* dp =
            (const float4*)&hdst[(((size_t)b * H_ + h) * N_ + (valid ? j : 0)) * U_];
        const float qj = qv[((size_t)b * H_ + h) * NP + j];

        float av[8] = {0.f, 0.f, 0.f, 0.f, 0.f, 0.f, 0.f, 0.f};
#pragma unroll 1
        for (int kc = 0; kc < 8; ++kc) {
            float4 A = dp[kc * 2 + 0];
            float4 Bv = dp[kc * 2 + 1];
            f32x2 dvp[4];
            dvp[0] = (f32x2){A.x, A.y};  dvp[1] = (f32x2){A.z, A.w};
            dvp[2] = (f32x2){Bv.x, Bv.y}; dvp[3] = (f32x2){Bv.z, Bv.w};
            const int o = kc * 8;
#pragma unroll
            for (int p = 0; p < 4; ++p) {
                const float a_lo = ap[o + p * 2];
                const float a_hi = ap[o + p * 2 + 1];
#pragma unroll
                for (int r = 0; r < 8; ++r) {
                    f32x2 t2 = pk_add_sv(sr8[r][kc * 4 + p], dvp[p]);
                    av[r] = fmaf(fabsf(t2.x), a_lo, av[r]);
                    av[r] = fmaf(fabsf(t2.y), a_hi, av[r]);
                }
            }
        }
        const float q6 = 0.6f * qj;
        float sc[8];
#pragma unroll
        for (int r = 0; r < 8; ++r)
            sc[r] = valid ? fmaf(0.4f, av[r], q6) : -1e30f;

        const int wave = tid >> 6, lane = tid & 63;
#pragma unroll
        for (int r = 0; r < 8; ++r) {
            float m = sc[r];
            for (int off = 1; off < 64; off <<= 1) m = fmaxf(m, __shfl_xor(m, off));
            if (lane == 0) red[wave * 8 + r] = m;
        }
        __syncthreads();
        if (tid < 8) {
            float mm = red[tid];
            for (int w = 1; w < 8; ++w) mm = fmaxf(mm, red[w * 8 + tid]);
            s_mx[tid] = mm;
        }
        __syncthreads();
        float e[8];
#pragma unroll
        for (int r = 0; r < 8; ++r) {
            e[r] = __expf(sc[r] - s_mx[r]);
            float s = e[r];
            for (int off = 1; off < 64; off <<= 1) s += __shfl_xor(s, off);
            if (lane == 0) red[wave * 8 + r] = s;
        }
        __syncthreads();
        if (tid < 8) {
            float ss = 0.f;
            for (int w = 0; w < 8; ++w) ss += red[w * 8 + tid];
            s_rs[tid] = 1.0f / ss;
        }
        __syncthreads();
#pragma unroll
        for (int r = 0; r < 8; ++r)
            attnB[(((size_t)b * H_ + h) * NP + i0 + r) * NP + j] =
                f2bf(e[r] * s_rs[r]);
    }
}

// ---------------------------------------------------------------------------
// attn standalone (fallback path only; identical body)
__global__ void __launch_bounds__(512) attn_softmax9(
    const float* __restrict__ hsrc, const float* __restrict__ hdst,
    const float* __restrict__ a_all, const float* __restrict__ qv,
    ushort* __restrict__ attnB)
{
    const int i0 = blockIdx.x * 8, b = blockIdx.y, h = blockIdx.z;
    const int tid = threadIdx.x;
    __shared__ float red[8 * 8];
    __shared__ float s_mx[8], s_rs[8];

    const float* ap = a_all + (size_t)h * U_;
    const float* hb = hsrc + (((size_t)b * H_ + h) * N_) * U_;
    const unsigned long long* sr8[8];
#pragma unroll
    for (int r = 0; r < 8; ++r)
        sr8[r] = (const unsigned long long*)
            (hb + (size_t)min(i0 + r, N_ - 1) * U_);

    const int j = tid;
    const bool valid = j < N_;
    const float4* dp =
        (const float4*)&hdst[(((size_t)b * H_ + h) * N_ + (valid ? j : 0)) * U_];
    const float qj = qv[((size_t)b * H_ + h) * NP + j];

    float av[8] = {0.f, 0.f, 0.f, 0.f, 0.f, 0.f, 0.f, 0.f};
#pragma unroll 1
    for (int kc = 0; kc < 8; ++kc) {
        const int o = kc * 8;
        float4 A = dp[kc * 2 + 0];
        float4 Bv = dp[kc * 2 + 1];
        f32x2 dvp[4];
        dvp[0] = (f32x2){A.x, A.y};  dvp[1] = (f32x2){A.z, A.w};
        dvp[2] = (f32x2){Bv.x, Bv.y}; dvp[3] = (f32x2){Bv.z, Bv.w};
#pragma unroll
        for (int p = 0; p < 4; ++p) {
            const float a_lo = ap[o + p * 2];
            const float a_hi = ap[o + p * 2 + 1];
#pragma unroll
            for (int r = 0; r < 8; ++r) {
                f32x2 t = pk_add_sv(sr8[r][kc * 4 + p], dvp[p]);
                av[r] = fmaf(fabsf(t.x), a_lo, av[r]);
                av[r] = fmaf(fabsf(t.y), a_hi, av[r]);
            }
        }
    }
    const float q6 = 0.6f * qj;
    float sc[8];
#pragma unroll
    for (int r = 0; r < 8; ++r)
        sc[r] = valid ? fmaf(0.4f, av[r], q6) : -1e30f;

    const int wave = tid >> 6, lane = tid & 63;
#pragma unroll
    for (int r = 0; r < 8; ++r) {
        float m = sc[r];
        for (int off = 1; off < 64; off <<= 1) m = fmaxf(m, __shfl_xor(m, off));
        if (lane == 0) red[wave * 8 + r] = m;
    }
    __syncthreads();
    if (tid < 8) {
        float mm = red[tid];
        for (int w = 1; w < 8; ++w) mm = fmaxf(mm, red[w * 8 + tid]);
        s_mx[tid] = mm;
    }
    __syncthreads();
    float e[8];
#pragma unroll
    for (int r = 0; r < 8; ++r) {
        e[r] = __expf(sc[r] - s_mx[r]);
        float s = e[r];
        for (int off = 1; off < 64; off <<= 1) s += __shfl_xor(s, off);
        if (lane == 0) red[wave * 8 + r] = s;
    }
    __syncthreads();
    if (tid < 8) {
        float ss = 0.f;
        for (int w = 0; w < 8; ++w) ss += red[w * 8 + tid];
        s_rs[tid] = 1.0f / ss;
    }
    __syncthreads();
#pragma unroll
    for (int r = 0; r < 8; ++r)
        attnB[(((size_t)b * H_ + h) * NP + i0 + r) * NP + j] =
            f2bf(e[r] * s_rs[r]);
}

// ---------------------------------------------------------------------------
// GEMM v3 (R10-verified): 512 threads / 8 waves, 128x128 tile, async16+swz.
__global__ void __launch_bounds__(512) gemm_big3(
    const ushort* __restrict__ msgT, const ushort* __restrict__ attnB,
    float* __restrict__ out)
{
    __shared__ ushort As[128 * 64];
    __shared__ ushort Bs[128 * 64];
    const int tid = threadIdx.x;
    const int mt = blockIdx.x, nt = blockIdx.y, b = blockIdx.z;

    const int wave = tid >> 6, lane = tid & 63;
    const int r15 = lane & 15, quad = lane >> 4;
    const int wm = wave >> 2, wn = wave & 3;
    const int lrow = lane >> 3, lch = lane & 7;

    f32x4 acc[4][2] = {};
    for (int kk = 0; kk < K4; kk += 64) {
        const int hh = kk >> 9, ko = kk & (NP - 1);
        const ushort* Ab = msgT + (((size_t)b * H_ + hh) * COLS + mt * 128) * NP + ko;
        const ushort* Bb = attnB + (((size_t)b * H_ + hh) * NP + nt * 128) * NP + ko;
#pragma unroll
        for (int l = 0; l < 2; ++l) {
            const int R0 = wave * 16 + l * 8;
            const int row = R0 + lrow;
            const int gch = lch ^ (row & 7);
            async16(Ab + (size_t)row * NP + gch * 8, &As[R0 * 64]);
            async16(Bb + (size_t)row * NP + gch * 8, &Bs[R0 * 64]);
        }
        __syncthreads();
#pragma unroll
        for (int ks = 0; ks < 2; ++ks) {
            bf16x8 af[4], bg[2];
#pragma unroll
            for (int f = 0; f < 4; ++f) {
                int row = wm * 64 + f * 16 + r15;
                int c = (ks * 4 + quad) ^ (row & 7);
                af[f] = *(const bf16x8*)&As[row * 64 + c * 8];
            }
#pragma unroll
            for (int g = 0; g < 2; ++g) {
                int row = wn * 32 + g * 16 + r15;
                int c = (ks * 4 + quad) ^ (row & 7);
                bg[g] = *(const bf16x8*)&Bs[row * 64 + c * 8];
            }
#pragma unroll
            for (int f = 0; f < 4; ++f)
#pragma unroll
                for (int g = 0; g < 2; ++g)
                    acc[f][g] = MFMA(af[f], bg[g], acc[f][g], 0, 0, 0);
        }
        __syncthreads();
    }

    const int t = mt * 2 + wm;
#pragma unroll
    for (int f = 0; f < 4; ++f)
#pragma unroll
        for (int g = 0; g < 2; ++g) {
            int u = f * 16 + quad * 4;
            int i = nt * 128 + wn * 32 + g * 16 + r15;
            if (i < N_) {
                float4 v;
                v.x = acc[f][g][0]; v.y = acc[f][g][1];
                v.z = acc[f][g][2]; v.w = acc[f][g][3];
                *(float4*)&out[(((size_t)b * T_ + t) * N_ + i) * U_ + u] = v;
            }
        }
}

// ---------------------------------------------------------------------------
// FALLBACK (small ws): per-head msg + gemm, same layouts.
__global__ void __launch_bounds__(256) msg_mfma(
    const float* __restrict__ curr, const ushort* __restrict__ WTh,
    ushort* __restrict__ msgT)
{
    __shared__ ushort As[128 * 136];
    __shared__ ushort Bs[64 * 136];
    const int tid = threadIdx.x;
    const int m0 = blockIdx.x * 128, t = blockIdx.y, b = blockIdx.z;

    const float* cbase = curr + (size_t)(b * T_ + t) * N_ * DC;
#pragma unroll
    for (int it = 0; it < 16; ++it) {
        int e = it * 1024 + tid * 4;
        int r = e >> 7, c = e & 127;
        int gm = m0 + r;
        float4 v; v.x = v.y = v.z = v.w = 0.f;
        if (gm < N_) v = *(const float4*)&cbase[(size_t)gm * DC + c];
        ushort4 o;
        o.x = f2bf(v.x); o.y = f2bf(v.y); o.z = f2bf(v.z); o.w = f2bf(v.w);
        *(ushort4*)&As[r * 136 + c] = o;
    }
#pragma unroll
    for (int it = 0; it < 4; ++it) {
        int e = it * 2048 + tid * 8;
        int u = e >> 7, d = e & 127;
        *(uint4*)&Bs[u * 136 + d] = *(const uint4*)&WTh[u * 128 + d];
    }
    __syncthreads();

    const int wave = tid >> 6, lane = tid & 63;
    const int r15 = lane & 15, quad = lane >> 4;
    const int wm = wave >> 1, wu = wave & 1;

    f32x4 acc[4][2] = {};
#pragma unroll
    for (int ks = 0; ks < 4; ++ks) {
        bf16x8 af[4], bg[2];
#pragma unroll
        for (int f = 0; f < 4; ++f)
            af[f] = *(const bf16x8*)&As[(wm * 64 + f * 16 + r15) * 136 + ks * 32 + quad * 8];
#pragma unroll
        for (int g = 0; g < 2; ++g)
            bg[g] = *(const bf16x8*)&Bs[(wu * 32 + g * 16 + r15) * 136 + ks * 32 + quad * 8];
#pragma unroll
        for (int f = 0; f < 4; ++f)
#pragma unroll
            for (int g = 0; g < 2; ++g)
                acc[f][g] = MFMA(af[f], bg[g], acc[f][g], 0, 0, 0);
    }
#pragma unroll
    for (int f = 0; f < 4; ++f)
#pragma unroll
        for (int g = 0; g < 2; ++g) {
            int m = m0 + wm * 64 + f * 16 + quad * 4;
            int u = wu * 32 + g * 16 + r15;
            int col = t * U_ + u;
            ushort4 o;
            o.x = f2bf(acc[f][g][0]); o.y = f2bf(acc[f][g][1]);
            o.z = f2bf(acc[f][g][2]); o.w = f2bf(acc[f][g][3]);
            *(ushort4*)&msgT[((size_t)b * COLS + col) * NP + m] = o;
        }
}

__global__ void __launch_bounds__(256) gemm_mfma(
    const ushort* __restrict__ msgT, const ushort* __restrict__ attnB,
    float* __restrict__ out, int h, int init)
{
    __shared__ ushort As[64 * 72];
    __shared__ ushort Bs[64 * 72];
    const int tid = threadIdx.x;
    const int ct = blockIdx.x, it = blockIdx.y, b = blockIdx.z;

    const ushort* Ab = msgT + ((size_t)b * COLS + ct * 64) * NP;
    const ushort* Bb = attnB + (((size_t)b * H_ + h) * NP + it * 64) * NP;

    const int wave = tid >> 6, lane = tid & 63;
    const int r15 = lane & 15, quad = lane >> 4;
    const int wm = wave >> 1, wn = wave & 1;
    const int srow = tid >> 3, scol = (tid & 7) * 8;

    f32x4 acc[2][2] = {};
    for (int kk = 0; kk < NP; kk += 64) {
#pragma unroll
        for (int it2 = 0; it2 < 2; ++it2) {
            int rr = it2 * 32 + srow;
            *(uint4*)&As[rr * 72 + scol] = *(const uint4*)&Ab[(size_t)rr * NP + kk + scol];
            *(uint4*)&Bs[rr * 72 + scol] = *(const uint4*)&Bb[(size_t)rr * NP + kk + scol];
        }
        __syncthreads();
#pragma unroll
        for (int ks = 0; ks < 2; ++ks) {
            bf16x8 af[2], bg[2];
#pragma unroll
            for (int f = 0; f < 2; ++f)
                af[f] = *(const bf16x8*)&As[(wm * 32 + f * 16 + r15) * 72 + ks * 32 + quad * 8];
#pragma unroll
            for (int g = 0; g < 2; ++g)
                bg[g] = *(const bf16x8*)&Bs[(wn * 32 + g * 16 + r15) * 72 + ks * 32 + quad * 8];
#pragma unroll
            for (int f = 0; f < 2; ++f)
#pragma unroll
                for (int g = 0; g < 2; ++g)
                    acc[f][g] = MFMA(af[f], bg[g], acc[f][g], 0, 0, 0);
        }
        __syncthreads();
    }

    const int t = ct;
#pragma unroll
    for (int f = 0; f < 2; ++f)
#pragma unroll
        for (int g = 0; g < 2; ++g) {
            int u = wm * 32 + f * 16 + quad * 4;
            int i = it * 64 + wn * 32 + g * 16 + r15;
            if (i < N_) {
                float* op = out + (((size_t)b * T_ + t) * N_ + i) * U_ + u;
                float4 v;
                v.x = acc[f][g][0]; v.y = acc[f][g][1];
                v.z = acc[f][g][2]; v.w = acc[f][g][3];
                if (!init) {
                    float4 old = *(const float4*)op;
                    v.x += old.x; v.y += old.y; v.z += old.z; v.w += old.w;
                }
                *(float4*)op = v;
            }
        }
}

// ---------------------------------------------------------------------------
extern "C" void kernel_launch(void* const* d_in, const int* in_sizes, int n_in,
                              void* d_out, int out_size, void* d_ws, size_t ws_size,
                              hipStream_t stream)
{
    const float* prev = (const float*)d_in[0];
    const float* curr = (const float*)d_in[1];
    const float* Wsrc = (const float*)d_in[2];
    const float* Wdst = (const float*)d_in[3];
    const float* avec = (const float*)d_in[4];
    const float* Wmsg = (const float*)d_in[5];
    float* out = (float*)d_out;

    const size_t attnB_b = (size_t)B_ * H_ * NP * NP * 2;   // 16.78 MB
    const size_t msgT4_b = (size_t)B_ * H_ * COLS * NP * 2; // 67.1 MB
    const size_t msgT1_b = (size_t)B_ * COLS * NP * 2;      // 16.78 MB
    const size_t WT_b    = (size_t)H_ * U_ * DC * 2;
    const size_t hx_b    = (size_t)B_ * H_ * N_ * U_ * 4;   // 4.1 MB
    const size_t qv_b    = (size_t)B_ * H_ * NP * 4;        // 64 KB

    const bool fused = ws_size >= attnB_b + msgT4_b + WT_b + 2 * hx_b + qv_b;
    const size_t msg_b = fused ? msgT4_b : msgT1_b;

    ushort* attnB = (ushort*)d_ws;
    ushort* msgT  = (ushort*)((char*)d_ws + attnB_b);
    ushort* WT    = (ushort*)((char*)d_ws + attnB_b + msg_b);
    float*  hsrc  = (float*)((char*)WT + WT_b);
    float*  hdst  = (float*)((char*)hsrc + hx_b);
    float*  qv    = (float*)((char*)hdst + hx_b);

    proj_mfma<<<250, 512, 0, stream>>>(prev, Wsrc, Wdst, avec, Wmsg,
                                       hsrc, hdst, qv, WT);

    if (fused) {
        // attn (2048 blocks) + msg (1024 blocks) co-scheduled 2:1
        phase2<<<3072, 512, 0, stream>>>(hsrc, hdst, avec, qv, attnB,
                                         curr, WT, msgT);
        gemm_big3<<<dim3(16, 4, B_), 512, 0, stream>>>(msgT, attnB, out);
    } else {
        attn_softmax9<<<dim3(64, B_, H_), 512, 0, stream>>>(hsrc, hdst, avec, qv, attnB);
        for (int h = 0; h < H_; ++h) {
            msg_mfma<<<dim3(4, T_, B_), 256, 0, stream>>>(
                curr, WT + (size_t)h * U_ * DC, msgT);
            gemm_mfma<<<dim3(32, 8, B_), 256, 0, stream>>>(
                msgT, attnB, out, h, h == 0 ? 1 : 0);
        }
    }
}